// Round 17
// baseline (136.575 us; speedup 1.0000x reference)
//
#include <hip/hip_runtime.h>
#include <hip/hip_bf16.h>

typedef __attribute__((ext_vector_type(8))) short bf16x8;
typedef __attribute__((ext_vector_type(4))) float f32x4;
typedef __attribute__((ext_vector_type(2))) unsigned u32x2;
typedef __attribute__((ext_vector_type(4))) unsigned u32x4;
typedef unsigned short u16;

#define NEG_INF (-__builtin_inff())

// async global->LDS, 16B per lane. LDS dest must be wave-uniform (HW adds lane*16).
__device__ __forceinline__ void gload16(const void* g, void* l) {
  __builtin_amdgcn_global_load_lds(
      (const __attribute__((address_space(1))) void*)g,
      (__attribute__((address_space(3))) void*)l, 16, 0, 0);
}

__device__ __forceinline__ u16 f2b(float f) {
  union { float f; unsigned u; } v;
  v.f = f;
  unsigned r = v.u + 0x7fff + ((v.u >> 16) & 1);  // RNE
  return (u16)(r >> 16);
}

// pack two f32 -> two bf16 in one u32 (low = a, high = b)
__device__ __forceinline__ unsigned cvt_pk_bf16(float a, float b) {
  unsigned r;
  asm("v_cvt_pk_bf16_f32 %0, %1, %2" : "=v"(r) : "v"(a), "v"(b));
  return r;
}

// ---- fused prep: cvt x -> bf16 | transpose Wkqv | transpose Wo ------------
__global__ __launch_bounds__(256) void prep_kernel(
    const float* __restrict__ x, u16* __restrict__ xb,
    const float* __restrict__ Wkqv, u16* __restrict__ WkqvT,
    const float* __restrict__ Wo, u16* __restrict__ WoT) {
  __shared__ u16 t[32][33];
  const int bid = blockIdx.x;
  const int tid = threadIdx.x;
  if (bid < 4096) {  // cvt: 4 floats/thread
    const int i = bid * 256 + tid;
    float4 v = ((const float4*)x)[i];
    ushort2 a = {f2b(v.x), f2b(v.y)}, b = {f2b(v.z), f2b(v.w)};
    ((ushort2*)xb)[i * 2] = a;
    ((ushort2*)xb)[i * 2 + 1] = b;
    return;
  }
  const int tx = tid & 31, ty = tid >> 5;  // 32x8
  const float* src;
  u16* dst;
  int R, C, bx_, by;
  if (bid < 7168) {  // Wkqv: dst[h][c][r] = bf16(src[h][r][c])
    const int tt = bid - 4096;
    const int bz = tt / 192, rem = tt % 192;
    by = rem / 6; bx_ = rem % 6; R = 1024; C = 192;
    src = Wkqv + (size_t)bz * R * C;
    dst = WkqvT + (size_t)bz * R * C;
  } else {  // Wo
    const int tt = bid - 7168;
    by = tt >> 5; bx_ = tt & 31; R = 1024; C = 1024;
    src = Wo; dst = WoT;
  }
  const int c0 = bx_ * 32, r0 = by * 32;
  for (int i = ty; i < 32; i += 8)
    t[i][tx] = f2b(src[(size_t)(r0 + i) * C + c0 + tx]);
  __syncthreads();
  for (int i = ty; i < 32; i += 8)
    dst[(size_t)(c0 + i) * R + r0 + tx] = t[tx][i];
}

// ------- 128x128x32 bf16 GEMM mainloop, double-buffered + counted vmcnt ----
__device__ __forceinline__ void gemm_mainloop_128(
    const __hip_bfloat16* __restrict__ A, const __hip_bfloat16* __restrict__ Bt,
    int K, int m0, int n0, f32x4 acc[4][4], char* AsB, char* BsB) {
  const int tid = threadIdx.x;
  const int wave = tid >> 6, lane = tid & 63;
  const int lhi = lane >> 4, llo = lane & 15;
  const int wr = wave >> 1, wc = wave & 1;
  f32x4 z = {0.f, 0.f, 0.f, 0.f};
#pragma unroll
  for (int i = 0; i < 4; i++)
#pragma unroll
    for (int j = 0; j < 4; j++) acc[i][j] = z;

#define GSTAGE(c, kk)                                                          \
  {                                                                            \
    char* AsW = AsB + (c)*8192;                                                \
    char* BsW = BsB + (c)*8192;                                                \
    _Pragma("unroll") for (int i = 0; i < 2; i++) {                            \
      int cb = i * 256 + wave * 64;                                            \
      int cq = cb + lane;                                                      \
      gload16(A + ((size_t)(m0 + (cq >> 2)) * K + (kk) + (cq & 3) * 8),        \
              AsW + cb * 16);                                                  \
      gload16(Bt + ((size_t)(n0 + (cq >> 2)) * K + (kk) + (cq & 3) * 8),       \
              BsW + cb * 16);                                                  \
    }                                                                          \
  }

  GSTAGE(0, 0);
  int cur = 0;
  const int nk = K >> 5;
  for (int t = 0; t < nk; t++) {
    if (t + 1 < nk) {
      GSTAGE(cur ^ 1, (t + 1) * 32);
      asm volatile("s_waitcnt vmcnt(4)" ::: "memory");
    } else {
      asm volatile("s_waitcnt vmcnt(0)" ::: "memory");
    }
    __builtin_amdgcn_s_barrier();
    __builtin_amdgcn_sched_barrier(0);

    const char* Ar = AsB + cur * 8192;
    const char* Br = BsB + cur * 8192;
    bf16x8 a[4], b[4];
#pragma unroll
    for (int m4 = 0; m4 < 4; m4++)
      a[m4] = *(const bf16x8*)(Ar + (wr * 64 + m4 * 16 + llo) * 64 + lhi * 16);
#pragma unroll
    for (int n4 = 0; n4 < 4; n4++)
      b[n4] = *(const bf16x8*)(Br + (wc * 64 + n4 * 16 + llo) * 64 + lhi * 16);
#pragma unroll
    for (int m4 = 0; m4 < 4; m4++)
#pragma unroll
      for (int n4 = 0; n4 < 4; n4++)
        acc[m4][n4] =
            __builtin_amdgcn_mfma_f32_16x16x32_bf16(a[m4], b[n4], acc[m4][n4], 0, 0, 0);
    __builtin_amdgcn_sched_barrier(0);
    __builtin_amdgcn_s_barrier();
    cur ^= 1;
  }
#undef GSTAGE
}

// ------- 64x128x32 variant (2 blocks/CU for skinny-M GEMM) -----------------
__device__ __forceinline__ void gemm_mainloop_64x128(
    const __hip_bfloat16* __restrict__ A, const __hip_bfloat16* __restrict__ Bt,
    int K, int m0, int n0, f32x4 acc[2][4], char* AsB, char* BsB) {
  const int tid = threadIdx.x;
  const int wave = tid >> 6, lane = tid & 63;
  const int lhi = lane >> 4, llo = lane & 15;
  const int wr = wave >> 1, wc = wave & 1;
  f32x4 z = {0.f, 0.f, 0.f, 0.f};
#pragma unroll
  for (int i = 0; i < 2; i++)
#pragma unroll
    for (int j = 0; j < 4; j++) acc[i][j] = z;

#define GSTAGE64(c, kk)                                                        \
  {                                                                            \
    char* AsW = AsB + (c)*4096;                                                \
    char* BsW = BsB + (c)*8192;                                                \
    gload16(A + ((size_t)(m0 + (tid >> 2)) * K + (kk) + (tid & 3) * 8),        \
            AsW + (wave * 64) * 16);                                           \
    _Pragma("unroll") for (int i = 0; i < 2; i++) {                            \
      int cb = i * 256 + wave * 64;                                            \
      int cq = cb + lane;                                                      \
      gload16(Bt + ((size_t)(n0 + (cq >> 2)) * K + (kk) + (cq & 3) * 8),       \
              BsW + cb * 16);                                                  \
    }                                                                          \
  }

  GSTAGE64(0, 0);
  int cur = 0;
  const int nk = K >> 5;
  for (int t = 0; t < nk; t++) {
    if (t + 1 < nk) {
      GSTAGE64(cur ^ 1, (t + 1) * 32);
      asm volatile("s_waitcnt vmcnt(3)" ::: "memory");
    } else {
      asm volatile("s_waitcnt vmcnt(0)" ::: "memory");
    }
    __builtin_amdgcn_s_barrier();
    __builtin_amdgcn_sched_barrier(0);

    const char* Ar = AsB + cur * 4096;
    const char* Br = BsB + cur * 8192;
    bf16x8 a[2], b[4];
#pragma unroll
    for (int m2 = 0; m2 < 2; m2++)
      a[m2] = *(const bf16x8*)(Ar + (wr * 32 + m2 * 16 + llo) * 64 + lhi * 16);
#pragma unroll
    for (int n4 = 0; n4 < 4; n4++)
      b[n4] = *(const bf16x8*)(Br + (wc * 64 + n4 * 16 + llo) * 64 + lhi * 16);
#pragma unroll
    for (int m2 = 0; m2 < 2; m2++)
#pragma unroll
      for (int n4 = 0; n4 < 4; n4++)
        acc[m2][n4] =
            __builtin_amdgcn_mfma_f32_16x16x32_bf16(a[m2], b[n4], acc[m2][n4], 0, 0, 0);
    __builtin_amdgcn_sched_barrier(0);
    __builtin_amdgcn_s_barrier();
    cur ^= 1;
  }
#undef GSTAGE64
}

// ------------- GEMM1: kqv = x @ WkqvT^T + bkqv, scatter to K/Q/Vt ----------
__global__ __launch_bounds__(256) void kqv_gemm(
    const __hip_bfloat16* __restrict__ x, const __hip_bfloat16* __restrict__ WT,
    const float* __restrict__ bkqv, __hip_bfloat16* __restrict__ Qb,
    __hip_bfloat16* __restrict__ Kb, __hip_bfloat16* __restrict__ Vt) {
  __shared__ __align__(16) char ldsbuf[34816];  // mainloop 32KB | Vsw 128x136 u16
  const int m0 = blockIdx.y * 128, n0 = blockIdx.x * 128;
  f32x4 acc[4][4];
  gemm_mainloop_128(x, WT, 1024, m0, n0, acc, ldsbuf, ldsbuf + 16384);

  const int tid = threadIdx.x, wave = tid >> 6, lane = tid & 63;
  const int lhi = lane >> 4, llo = lane & 15;
  const int wr = wave >> 1, wc = wave & 1;
  u16* Vsw = (u16*)ldsbuf;  // [row 0..127][136] padded (reuse after barrier)
#pragma unroll
  for (int m4 = 0; m4 < 4; m4++)
#pragma unroll
    for (int n4 = 0; n4 < 4; n4++)
#pragma unroll
      for (int r = 0; r < 4; r++) {
        int sp = wr * 64 + m4 * 16 + lhi * 4 + r;   // s - m0
        int row = wc * 64 + n4 * 16 + llo;          // ng - n0
        int mg = m0 + sp;
        int ng = n0 + row;
        int b = mg >> 11, s = mg & 2047;
        int h = ng / 192, f = ng % 192;
        float v = acc[m4][n4][r] + bkqv[h * 192 + f];
        int d = f & 63;
        size_t bh = (size_t)(b * 16 + h);
        if (f < 64)
          Kb[(bh * 2048 + s) * 64 + d] = __float2bfloat16(v);
        else if (f < 128)
          Qb[(bh * 2048 + s) * 64 + d] = __float2bfloat16(v * 0.180336880f);
        else
          Vsw[row * 136 + sp] = f2b(v);
      }
  __syncthreads();
  // coalesced Vt store: each row (V-chunk only) = 256B contiguous in global
#pragma unroll
  for (int it = 0; it < 8; it++) {
    int task = it * 256 + tid;
    int row = task >> 4, c = task & 15;
    int ng = n0 + row, f = ng % 192;
    if (f >= 128) {
      int h = ng / 192, d = f - 128;
      int mg0 = m0 + c * 8;
      int b = mg0 >> 11, s = mg0 & 2047;
      size_t bh = (size_t)(b * 16 + h);
      u32x4 w = *(const u32x4*)&Vsw[row * 136 + c * 8];
      *(u32x4*)((u16*)Vt + (size_t)(bh * 64 + d) * 2048 + s) = w;
    }
  }
}

// ---- per-chunk softmax + in-register P pack (verified R12/R15 body) -------
__device__ __forceinline__ void softmax_pack(
    f32x4* s, bool masked, int k0, int qg, int lhi4,
    float& m_s, float& l_s, f32x4* o, bf16x8& ap0, bf16x8& ap1) {
  if (masked) {
#pragma unroll
    for (int jj = 0; jj < 4; jj++)
#pragma unroll
      for (int r = 0; r < 4; r++)
        if (k0 + jj * 16 + lhi4 + r > qg) s[jj][r] = NEG_INF;
  }
  float pmax = s[0][0];
#pragma unroll
  for (int jj = 0; jj < 4; jj++)
#pragma unroll
    for (int r = 0; r < 4; r++) pmax = fmaxf(pmax, s[jj][r]);
  {  // reduce across the 4 lhi lanes via permlane swaps (VALU, no DS)
    union { float f; unsigned u; } pu;
    pu.f = pmax;
    u32x2 sp = __builtin_amdgcn_permlane32_swap(pu.u, pu.u, false, false);
    float m1 = fmaxf(__uint_as_float(sp.x), __uint_as_float(sp.y));
    union { float f; unsigned u; } mu;
    mu.f = m1;
    u32x2 tp = __builtin_amdgcn_permlane16_swap(mu.u, mu.u, false, false);
    pmax = fmaxf(__uint_as_float(tp.x), __uint_as_float(tp.y));
  }
  if (!__all(pmax - m_s <= 5.0f)) {  // defer-max: rescale rarely
    const float mn = fmaxf(m_s, pmax);
    const float sc = __builtin_exp2f(m_s - mn);
    m_s = mn;
    l_s *= sc;
#pragma unroll
    for (int r = 0; r < 4; r++) {
      const float scr = __shfl(sc, lhi4 + r);
#pragma unroll
      for (int n4 = 0; n4 < 4; n4++) o[n4][r] *= scr;
    }
  }
  unsigned pk[4][2];
  float ps = 0.f;
#pragma unroll
  for (int jj = 0; jj < 4; jj++) {
    float p0 = __builtin_exp2f(s[jj][0] - m_s);
    float p1 = __builtin_exp2f(s[jj][1] - m_s);
    float p2 = __builtin_exp2f(s[jj][2] - m_s);
    float p3 = __builtin_exp2f(s[jj][3] - m_s);
    ps += (p0 + p1) + (p2 + p3);
    pk[jj][0] = cvt_pk_bf16(p0, p1);
    pk[jj][1] = cvt_pk_bf16(p2, p3);
  }
  l_s += ps;

  u32x4 a0w, a1w;
#pragma unroll
  for (int u = 0; u < 2; u++) {
    u32x2 sp = __builtin_amdgcn_permlane32_swap(pk[0][u], pk[1][u], false, false);
    u32x2 tp = __builtin_amdgcn_permlane16_swap(sp.x, sp.y, false, false);
    a0w[u] = tp.x;
    a0w[u + 2] = tp.y;
  }
#pragma unroll
  for (int u = 0; u < 2; u++) {
    u32x2 sp = __builtin_amdgcn_permlane32_swap(pk[2][u], pk[3][u], false, false);
    u32x2 tp = __builtin_amdgcn_permlane16_swap(sp.x, sp.y, false, false);
    a1w[u] = tp.x;
    a1w[u + 2] = tp.y;
  }
  ap0 = __builtin_bit_cast(bf16x8, a0w);
  ap1 = __builtin_bit_cast(bf16x8, a1w);
}

// ------------------- causal flash attention, D=64 --------------------------
// DOUBLE-Q, 2-WAVE BLOCKS: each wave owns 32 q-rows (two 16-q chunks sharing
// all K/V LDS fragment reads -> per-q-row LDS-read traffic halved vs R12).
// Block = 2 waves = 64 q-rows; grid 1024 (4-5 blocks/CU at 32KB LDS).
// KVBLK=64 double-buffered gload_lds, vmcnt(8); swapped QK^T; in-register P;
// defer-max; exp2 domain. Both chunks active for all T<=qt (no divergence);
// masking only on the diagonal tile.
__global__ __launch_bounds__(128) void attn_kernel(
    const __hip_bfloat16* __restrict__ Qb, const __hip_bfloat16* __restrict__ Kb,
    const __hip_bfloat16* __restrict__ Vt, __hip_bfloat16* __restrict__ SA) {
  __shared__ __align__(16) char lds[32768];  // Ks 2x8K | Vs 2x8K
  const int orig = blockIdx.x;
  const int bh = (orig & 7) * 4 + ((orig >> 3) & 3);  // 4 bh per XCD
  const int qt = 31 - (orig >> 5);                    // heavy first (LPT)
  const int nt = qt + 1;
  const int b = bh >> 4, h = bh & 15;
  const int tid = threadIdx.x, wave = tid >> 6, lane = tid & 63;
  const int lhi = lane >> 4, llo = lane & 15;
  const int lhi4 = lhi * 4;
  const int wbase = qt * 64 + wave * 32;

  // Q frags, both chunks (Q pre-scaled by 0.125*log2e in kqv_gemm)
  const __hip_bfloat16* qp =
      Qb + ((size_t)bh * 2048 + wbase + llo) * 64 + lhi * 8;
  bf16x8 qA0 = *(const bf16x8*)qp, qA1 = *(const bf16x8*)(qp + 32);
  bf16x8 qB0 = *(const bf16x8*)(qp + 16 * 64);
  bf16x8 qB1 = *(const bf16x8*)(qp + 16 * 64 + 32);

  const char* Kg = (const char*)(Kb + (size_t)bh * 2048 * 64);
  const char* Vg = (const char*)(Vt + (size_t)bh * 64 * 2048);

  f32x4 z = {0.f, 0.f, 0.f, 0.f};
  f32x4 o0[4], o1[4];
  float m0 = NEG_INF, l0 = 0.f, m1 = NEG_INF, l1 = 0.f;
#pragma unroll
  for (int i = 0; i < 4; i++) { o0[i] = z; o1[i] = z; }
  const int qg_0 = wbase + llo, qg_1 = wbase + 16 + llo;

  // stage 64-key tile into buffer c: 128 threads, 8 gload16/lane (4 K + 4 V)
#define STAGE(c, k0)                                                          \
  {                                                                           \
    char* KsW = lds + (c)*8192;                                               \
    char* VsW = lds + 16384 + (c)*8192;                                       \
    _Pragma("unroll") for (int i = 0; i < 4; i++) {                           \
      int ch = i * 128 + tid;                                                 \
      int soff = (ch * 16) ^ (((ch >> 3) & 7) << 4);                          \
      gload16(Kg + (size_t)(k0)*128 + soff, KsW + (i * 128 + wave * 64) * 16);\
      int dd = ch >> 3, c8 = ch & 7;                                          \
      int boff = (c8 * 16) ^ ((dd & 7) << 4);                                 \
      gload16(Vg + (size_t)dd * 4096 + (size_t)(k0)*2 + boff,                 \
              VsW + (i * 128 + wave * 64) * 16);                              \
    }                                                                         \
  }

  STAGE(0, 0);
  int cur = 0;

  for (int T = 0; T < nt; T++) {
    if (T + 1 < nt) {
      STAGE(cur ^ 1, (T + 1) * 64);
      asm volatile("s_waitcnt vmcnt(8)" ::: "memory");
    } else {
      asm volatile("s_waitcnt vmcnt(0)" ::: "memory");
    }
    __builtin_amdgcn_s_barrier();
    __builtin_amdgcn_sched_barrier(0);

    const int k0 = T * 64;
    const bool masked = (T == nt - 1);  // only the diagonal tile masks
    const char* KsB = lds + cur * 8192;
    const char* VsB = lds + 16384 + cur * 8192;

    // ---- QK^T swapped, both chunks share K-fragment reads ----
    f32x4 s[4] = {z, z, z, z}, t[4] = {z, z, z, z};
#pragma unroll
    for (int jj = 0; jj < 4; jj++) {
      const int row = jj * 16 + llo;
      const int rx = (row & 7) << 4;
      bf16x8 bk0 = *(const bf16x8*)(KsB + ((row * 128 + lhi * 16) ^ rx));
      bf16x8 bk1 = *(const bf16x8*)(KsB + ((row * 128 + 64 + lhi * 16) ^ rx));
      __builtin_amdgcn_s_setprio(1);
      s[jj] = __builtin_amdgcn_mfma_f32_16x16x32_bf16(bk0, qA0, s[jj], 0, 0, 0);
      s[jj] = __builtin_amdgcn_mfma_f32_16x16x32_bf16(bk1, qA1, s[jj], 0, 0, 0);
      t[jj] = __builtin_amdgcn_mfma_f32_16x16x32_bf16(bk0, qB0, t[jj], 0, 0, 0);
      t[jj] = __builtin_amdgcn_mfma_f32_16x16x32_bf16(bk1, qB1, t[jj], 0, 0, 0);
      __builtin_amdgcn_s_setprio(0);
    }

    // ---- softmax + P pack per chunk ----
    bf16x8 ap0_0, ap1_0, ap0_1, ap1_1;
    softmax_pack(s, masked, k0, qg_0, lhi4, m0, l0, o0, ap0_0, ap1_0);
    softmax_pack(t, masked, k0, qg_1, lhi4, m1, l1, o1, ap0_1, ap1_1);

    // ---- PV: both chunks share V-fragment reads ----
#pragma unroll
    for (int n4 = 0; n4 < 4; n4++) {
      const int d = n4 * 16 + llo;
      const int dx = (d & 7) << 4;
      bf16x8 bv0 = *(const bf16x8*)(VsB + ((d * 128 + lhi * 16) ^ dx));
      bf16x8 bv1 = *(const bf16x8*)(VsB + ((d * 128 + 64 + lhi * 16) ^ dx));
      __builtin_amdgcn_s_setprio(1);
      o0[n4] = __builtin_amdgcn_mfma_f32_16x16x32_bf16(ap0_0, bv0, o0[n4], 0, 0, 0);
      o0[n4] = __builtin_amdgcn_mfma_f32_16x16x32_bf16(ap1_0, bv1, o0[n4], 0, 0, 0);
      o1[n4] = __builtin_amdgcn_mfma_f32_16x16x32_bf16(ap0_1, bv0, o1[n4], 0, 0, 0);
      o1[n4] = __builtin_amdgcn_mfma_f32_16x16x32_bf16(ap1_1, bv1, o1[n4], 0, 0, 0);
      __builtin_amdgcn_s_setprio(0);
    }
    __builtin_amdgcn_sched_barrier(0);
    __builtin_amdgcn_s_barrier();  // all waves done reading buf[cur]
    cur ^= 1;
  }

  // epilogue per chunk: reduce l across lhi lanes, normalize, store
#pragma unroll
  for (int c = 0; c < 2; c++) {
    float l_s = c ? l1 : l0;
    f32x4* o = c ? o1 : o0;
    const int qg0 = wbase + 16 * c + lhi4;
    union { float f; unsigned u; } lu;
    lu.f = l_s;
    u32x2 sp = __builtin_amdgcn_permlane32_swap(lu.u, lu.u, false, false);
    float ls1 = __uint_as_float(sp.x) + __uint_as_float(sp.y);
    union { float f; unsigned u; } l2u;
    l2u.f = ls1;
    u32x2 tp = __builtin_amdgcn_permlane16_swap(l2u.u, l2u.u, false, false);
    const float l = __uint_as_float(tp.x) + __uint_as_float(tp.y);
    const float inv = 1.f / l;
#pragma unroll
    for (int r = 0; r < 4; r++) {
      const float invr = __shfl(inv, lhi4 + r);
      const size_t ob = ((size_t)b * 2048 + qg0 + r) * 1024 + h * 64;
#pragma unroll
      for (int n4 = 0; n4 < 4; n4++)
        SA[ob + n4 * 16 + llo] = __float2bfloat16(o[n4][r] * invr);
    }
  }
#undef STAGE
}

// ------------- GEMM3: out = SA @ Wo + bo (fp32 out; 64x128 tiles) ----------
__global__ __launch_bounds__(256) void out_gemm(
    const __hip_bfloat16* __restrict__ SA, const __hip_bfloat16* __restrict__ WoT,
    const float* __restrict__ bo, float* __restrict__ out) {
  __shared__ __align__(16) char As[8192];
  __shared__ __align__(16) char Bs[16384];
  const int m0 = blockIdx.y * 64, n0 = blockIdx.x * 128;
  f32x4 acc[2][4];
  gemm_mainloop_64x128(SA, WoT, 1024, m0, n0, acc, As, Bs);

  const int tid = threadIdx.x, wave = tid >> 6, lane = tid & 63;
  const int lhi = lane >> 4, llo = lane & 15;
  const int wr = wave >> 1, wc = wave & 1;
#pragma unroll
  for (int m2 = 0; m2 < 2; m2++)
#pragma unroll
    for (int n4 = 0; n4 < 4; n4++)
#pragma unroll
      for (int r = 0; r < 4; r++) {
        int mg = m0 + wr * 32 + m2 * 16 + lhi * 4 + r;
        int ng = n0 + wc * 64 + n4 * 16 + llo;
        out[(size_t)mg * 1024 + ng] = acc[m2][n4][r] + bo[ng];
      }
}

extern "C" void kernel_launch(void* const* d_in, const int* in_sizes, int n_in,
                              void* d_out, int out_size, void* d_ws, size_t ws_size,
                              hipStream_t stream) {
  const float* x = (const float*)d_in[0];
  const float* Wkqv = (const float*)d_in[1];
  const float* bkqv = (const float*)d_in[2];
  const float* Wo = (const float*)d_in[3];
  const float* bo = (const float*)d_in[4];
  float* out = (float*)d_out;  // fp32 output (verified R5)

  char* w = (char*)d_ws;
  __hip_bfloat16* WkqvT = (__hip_bfloat16*)(w);            // 3072x1024  (6 MB)
  __hip_bfloat16* WoT = (__hip_bfloat16*)(w + 6291456);    // 1024x1024  (2 MB)
  __hip_bfloat16* Qb = (__hip_bfloat16*)(w + 8388608);     // [B][H][S][64] (8 MB)
  __hip_bfloat16* Kb = (__hip_bfloat16*)(w + 16777216);    // [B][H][S][64] (8 MB)
  __hip_bfloat16* Vt = (__hip_bfloat16*)(w + 25165824);    // [B][H][64][S] (8 MB)
  __hip_bfloat16* SAb = (__hip_bfloat16*)(w + 33554432);   // [B][S][E]     (8 MB)
  __hip_bfloat16* xb = (__hip_bfloat16*)(w + 41943040);    // [B][S][E]     (8 MB)

  prep_kernel<<<8192, 256, 0, stream>>>(x, (u16*)xb, Wkqv, (u16*)WkqvT,
                                        Wo, (u16*)WoT);
  kqv_gemm<<<dim3(24, 32), 256, 0, stream>>>(xb, WkqvT, bkqv, Qb, Kb, Vt);
  attn_kernel<<<1024, 128, 0, stream>>>(Qb, Kb, Vt, SAb);
  out_gemm<<<dim3(8, 64), 256, 0, stream>>>(SAb, WoT, bo, out);
}

// Round 18
// 119.580 us; speedup vs baseline: 1.1421x; 1.1421x over previous
//
#include <hip/hip_runtime.h>
#include <hip/hip_bf16.h>

typedef __attribute__((ext_vector_type(8))) short bf16x8;
typedef __attribute__((ext_vector_type(4))) float f32x4;
typedef __attribute__((ext_vector_type(2))) unsigned u32x2;
typedef __attribute__((ext_vector_type(4))) unsigned u32x4;
typedef unsigned short u16;

#define NEG_INF (-__builtin_inff())

// async global->LDS, 16B per lane. LDS dest must be wave-uniform (HW adds lane*16).
__device__ __forceinline__ void gload16(const void* g, void* l) {
  __builtin_amdgcn_global_load_lds(
      (const __attribute__((address_space(1))) void*)g,
      (__attribute__((address_space(3))) void*)l, 16, 0, 0);
}

__device__ __forceinline__ u16 f2b(float f) {
  union { float f; unsigned u; } v;
  v.f = f;
  unsigned r = v.u + 0x7fff + ((v.u >> 16) & 1);  // RNE
  return (u16)(r >> 16);
}

// pack two f32 -> two bf16 in one u32 (low = a, high = b)
__device__ __forceinline__ unsigned cvt_pk_bf16(float a, float b) {
  unsigned r;
  asm("v_cvt_pk_bf16_f32 %0, %1, %2" : "=v"(r) : "v"(a), "v"(b));
  return r;
}

// ---- fused prep: cvt x -> bf16 | transpose Wkqv | transpose Wo ------------
__global__ __launch_bounds__(256) void prep_kernel(
    const float* __restrict__ x, u16* __restrict__ xb,
    const float* __restrict__ Wkqv, u16* __restrict__ WkqvT,
    const float* __restrict__ Wo, u16* __restrict__ WoT) {
  __shared__ u16 t[32][33];
  const int bid = blockIdx.x;
  const int tid = threadIdx.x;
  if (bid < 4096) {  // cvt: 4 floats/thread
    const int i = bid * 256 + tid;
    float4 v = ((const float4*)x)[i];
    ushort2 a = {f2b(v.x), f2b(v.y)}, b = {f2b(v.z), f2b(v.w)};
    ((ushort2*)xb)[i * 2] = a;
    ((ushort2*)xb)[i * 2 + 1] = b;
    return;
  }
  const int tx = tid & 31, ty = tid >> 5;  // 32x8
  const float* src;
  u16* dst;
  int R, C, bx_, by;
  if (bid < 7168) {  // Wkqv: dst[h][c][r] = bf16(src[h][r][c])
    const int tt = bid - 4096;
    const int bz = tt / 192, rem = tt % 192;
    by = rem / 6; bx_ = rem % 6; R = 1024; C = 192;
    src = Wkqv + (size_t)bz * R * C;
    dst = WkqvT + (size_t)bz * R * C;
  } else {  // Wo
    const int tt = bid - 7168;
    by = tt >> 5; bx_ = tt & 31; R = 1024; C = 1024;
    src = Wo; dst = WoT;
  }
  const int c0 = bx_ * 32, r0 = by * 32;
  for (int i = ty; i < 32; i += 8)
    t[i][tx] = f2b(src[(size_t)(r0 + i) * C + c0 + tx]);
  __syncthreads();
  for (int i = ty; i < 32; i += 8)
    dst[(size_t)(c0 + i) * R + r0 + tx] = t[tx][i];
}

// ------- 128x128x32 bf16 GEMM mainloop, double-buffered + counted vmcnt ----
__device__ __forceinline__ void gemm_mainloop_128(
    const __hip_bfloat16* __restrict__ A, const __hip_bfloat16* __restrict__ Bt,
    int K, int m0, int n0, f32x4 acc[4][4], char* AsB, char* BsB) {
  const int tid = threadIdx.x;
  const int wave = tid >> 6, lane = tid & 63;
  const int lhi = lane >> 4, llo = lane & 15;
  const int wr = wave >> 1, wc = wave & 1;
  f32x4 z = {0.f, 0.f, 0.f, 0.f};
#pragma unroll
  for (int i = 0; i < 4; i++)
#pragma unroll
    for (int j = 0; j < 4; j++) acc[i][j] = z;

#define GSTAGE(c, kk)                                                          \
  {                                                                            \
    char* AsW = AsB + (c)*8192;                                                \
    char* BsW = BsB + (c)*8192;                                                \
    _Pragma("unroll") for (int i = 0; i < 2; i++) {                            \
      int cb = i * 256 + wave * 64;                                            \
      int cq = cb + lane;                                                      \
      gload16(A + ((size_t)(m0 + (cq >> 2)) * K + (kk) + (cq & 3) * 8),        \
              AsW + cb * 16);                                                  \
      gload16(Bt + ((size_t)(n0 + (cq >> 2)) * K + (kk) + (cq & 3) * 8),       \
              BsW + cb * 16);                                                  \
    }                                                                          \
  }

  GSTAGE(0, 0);
  int cur = 0;
  const int nk = K >> 5;
  for (int t = 0; t < nk; t++) {
    if (t + 1 < nk) {
      GSTAGE(cur ^ 1, (t + 1) * 32);
      asm volatile("s_waitcnt vmcnt(4)" ::: "memory");
    } else {
      asm volatile("s_waitcnt vmcnt(0)" ::: "memory");
    }
    __builtin_amdgcn_s_barrier();
    __builtin_amdgcn_sched_barrier(0);

    const char* Ar = AsB + cur * 8192;
    const char* Br = BsB + cur * 8192;
    bf16x8 a[4], b[4];
#pragma unroll
    for (int m4 = 0; m4 < 4; m4++)
      a[m4] = *(const bf16x8*)(Ar + (wr * 64 + m4 * 16 + llo) * 64 + lhi * 16);
#pragma unroll
    for (int n4 = 0; n4 < 4; n4++)
      b[n4] = *(const bf16x8*)(Br + (wc * 64 + n4 * 16 + llo) * 64 + lhi * 16);
#pragma unroll
    for (int m4 = 0; m4 < 4; m4++)
#pragma unroll
      for (int n4 = 0; n4 < 4; n4++)
        acc[m4][n4] =
            __builtin_amdgcn_mfma_f32_16x16x32_bf16(a[m4], b[n4], acc[m4][n4], 0, 0, 0);
    __builtin_amdgcn_sched_barrier(0);
    __builtin_amdgcn_s_barrier();
    cur ^= 1;
  }
#undef GSTAGE
}

// ------- 64x128x32 variant (2 blocks/CU for skinny-M GEMM) -----------------
__device__ __forceinline__ void gemm_mainloop_64x128(
    const __hip_bfloat16* __restrict__ A, const __hip_bfloat16* __restrict__ Bt,
    int K, int m0, int n0, f32x4 acc[2][4], char* AsB, char* BsB) {
  const int tid = threadIdx.x;
  const int wave = tid >> 6, lane = tid & 63;
  const int lhi = lane >> 4, llo = lane & 15;
  const int wr = wave >> 1, wc = wave & 1;
  f32x4 z = {0.f, 0.f, 0.f, 0.f};
#pragma unroll
  for (int i = 0; i < 2; i++)
#pragma unroll
    for (int j = 0; j < 4; j++) acc[i][j] = z;

#define GSTAGE64(c, kk)                                                        \
  {                                                                            \
    char* AsW = AsB + (c)*4096;                                                \
    char* BsW = BsB + (c)*8192;                                                \
    gload16(A + ((size_t)(m0 + (tid >> 2)) * K + (kk) + (tid & 3) * 8),        \
            AsW + (wave * 64) * 16);                                           \
    _Pragma("unroll") for (int i = 0; i < 2; i++) {                            \
      int cb = i * 256 + wave * 64;                                            \
      int cq = cb + lane;                                                      \
      gload16(Bt + ((size_t)(n0 + (cq >> 2)) * K + (kk) + (cq & 3) * 8),       \
              BsW + cb * 16);                                                  \
    }                                                                          \
  }

  GSTAGE64(0, 0);
  int cur = 0;
  const int nk = K >> 5;
  for (int t = 0; t < nk; t++) {
    if (t + 1 < nk) {
      GSTAGE64(cur ^ 1, (t + 1) * 32);
      asm volatile("s_waitcnt vmcnt(3)" ::: "memory");
    } else {
      asm volatile("s_waitcnt vmcnt(0)" ::: "memory");
    }
    __builtin_amdgcn_s_barrier();
    __builtin_amdgcn_sched_barrier(0);

    const char* Ar = AsB + cur * 4096;
    const char* Br = BsB + cur * 8192;
    bf16x8 a[2], b[4];
#pragma unroll
    for (int m2 = 0; m2 < 2; m2++)
      a[m2] = *(const bf16x8*)(Ar + (wr * 32 + m2 * 16 + llo) * 64 + lhi * 16);
#pragma unroll
    for (int n4 = 0; n4 < 4; n4++)
      b[n4] = *(const bf16x8*)(Br + (wc * 64 + n4 * 16 + llo) * 64 + lhi * 16);
#pragma unroll
    for (int m2 = 0; m2 < 2; m2++)
#pragma unroll
      for (int n4 = 0; n4 < 4; n4++)
        acc[m2][n4] =
            __builtin_amdgcn_mfma_f32_16x16x32_bf16(a[m2], b[n4], acc[m2][n4], 0, 0, 0);
    __builtin_amdgcn_sched_barrier(0);
    __builtin_amdgcn_s_barrier();
    cur ^= 1;
  }
#undef GSTAGE64
}

// ------------- GEMM1: kqv = x @ WkqvT^T + bkqv, scatter to K/Q/Vt ----------
__global__ __launch_bounds__(256) void kqv_gemm(
    const __hip_bfloat16* __restrict__ x, const __hip_bfloat16* __restrict__ WT,
    const float* __restrict__ bkqv, __hip_bfloat16* __restrict__ Qb,
    __hip_bfloat16* __restrict__ Kb, __hip_bfloat16* __restrict__ Vt) {
  __shared__ __align__(16) char ldsbuf[34816];  // mainloop 32KB | Vsw 128x136 u16
  const int m0 = blockIdx.y * 128, n0 = blockIdx.x * 128;
  f32x4 acc[4][4];
  gemm_mainloop_128(x, WT, 1024, m0, n0, acc, ldsbuf, ldsbuf + 16384);

  const int tid = threadIdx.x, wave = tid >> 6, lane = tid & 63;
  const int lhi = lane >> 4, llo = lane & 15;
  const int wr = wave >> 1, wc = wave & 1;
  u16* Vsw = (u16*)ldsbuf;  // [row 0..127][136] padded (reuse after barrier)
#pragma unroll
  for (int m4 = 0; m4 < 4; m4++)
#pragma unroll
    for (int n4 = 0; n4 < 4; n4++)
#pragma unroll
      for (int r = 0; r < 4; r++) {
        int sp = wr * 64 + m4 * 16 + lhi * 4 + r;   // s - m0
        int row = wc * 64 + n4 * 16 + llo;          // ng - n0
        int mg = m0 + sp;
        int ng = n0 + row;
        int b = mg >> 11, s = mg & 2047;
        int h = ng / 192, f = ng % 192;
        float v = acc[m4][n4][r] + bkqv[h * 192 + f];
        int d = f & 63;
        size_t bh = (size_t)(b * 16 + h);
        if (f < 64)
          Kb[(bh * 2048 + s) * 64 + d] = __float2bfloat16(v);
        else if (f < 128)
          Qb[(bh * 2048 + s) * 64 + d] = __float2bfloat16(v * 0.180336880f);
        else
          Vsw[row * 136 + sp] = f2b(v);
      }
  __syncthreads();
  // coalesced Vt store: each row (V-chunk only) = 256B contiguous in global
#pragma unroll
  for (int it = 0; it < 8; it++) {
    int task = it * 256 + tid;
    int row = task >> 4, c = task & 15;
    int ng = n0 + row, f = ng % 192;
    if (f >= 128) {
      int h = ng / 192, d = f - 128;
      int mg0 = m0 + c * 8;
      int b = mg0 >> 11, s = mg0 & 2047;
      size_t bh = (size_t)(b * 16 + h);
      u32x4 w = *(const u32x4*)&Vsw[row * 136 + c * 8];
      *(u32x4*)((u16*)Vt + (size_t)(bh * 64 + d) * 2048 + s) = w;
    }
  }
}

// ---- per-chunk softmax + in-register P pack (verified R12 body) -----------
__device__ __forceinline__ void softmax_pack(
    f32x4* s, bool masked, int k0, int qg, int lhi4,
    float& m_s, float& l_s, f32x4* o, bf16x8& ap0, bf16x8& ap1) {
  if (masked) {
#pragma unroll
    for (int jj = 0; jj < 4; jj++)
#pragma unroll
      for (int r = 0; r < 4; r++)
        if (k0 + jj * 16 + lhi4 + r > qg) s[jj][r] = NEG_INF;
  }
  float pmax = s[0][0];
#pragma unroll
  for (int jj = 0; jj < 4; jj++)
#pragma unroll
    for (int r = 0; r < 4; r++) pmax = fmaxf(pmax, s[jj][r]);
  {  // reduce across the 4 lhi lanes via permlane swaps (VALU, no DS)
    union { float f; unsigned u; } pu;
    pu.f = pmax;
    u32x2 sp = __builtin_amdgcn_permlane32_swap(pu.u, pu.u, false, false);
    float m1 = fmaxf(__uint_as_float(sp.x), __uint_as_float(sp.y));
    union { float f; unsigned u; } mu;
    mu.f = m1;
    u32x2 tp = __builtin_amdgcn_permlane16_swap(mu.u, mu.u, false, false);
    pmax = fmaxf(__uint_as_float(tp.x), __uint_as_float(tp.y));
  }
  if (!__all(pmax - m_s <= 5.0f)) {  // defer-max: rescale rarely
    const float mn = fmaxf(m_s, pmax);
    const float sc = __builtin_exp2f(m_s - mn);
    m_s = mn;
    l_s *= sc;
#pragma unroll
    for (int r = 0; r < 4; r++) {
      const float scr = __shfl(sc, lhi4 + r);
#pragma unroll
      for (int n4 = 0; n4 < 4; n4++) o[n4][r] *= scr;
    }
  }
  unsigned pk[4][2];
  float ps = 0.f;
#pragma unroll
  for (int jj = 0; jj < 4; jj++) {
    float p0 = __builtin_exp2f(s[jj][0] - m_s);
    float p1 = __builtin_exp2f(s[jj][1] - m_s);
    float p2 = __builtin_exp2f(s[jj][2] - m_s);
    float p3 = __builtin_exp2f(s[jj][3] - m_s);
    ps += (p0 + p1) + (p2 + p3);
    pk[jj][0] = cvt_pk_bf16(p0, p1);
    pk[jj][1] = cvt_pk_bf16(p2, p3);
  }
  l_s += ps;

  u32x4 a0w, a1w;
#pragma unroll
  for (int u = 0; u < 2; u++) {
    u32x2 sp = __builtin_amdgcn_permlane32_swap(pk[0][u], pk[1][u], false, false);
    u32x2 tp = __builtin_amdgcn_permlane16_swap(sp.x, sp.y, false, false);
    a0w[u] = tp.x;
    a0w[u + 2] = tp.y;
  }
#pragma unroll
  for (int u = 0; u < 2; u++) {
    u32x2 sp = __builtin_amdgcn_permlane32_swap(pk[2][u], pk[3][u], false, false);
    u32x2 tp = __builtin_amdgcn_permlane16_swap(sp.x, sp.y, false, false);
    a1w[u] = tp.x;
    a1w[u + 2] = tp.y;
  }
  ap0 = __builtin_bit_cast(bf16x8, a0w);
  ap1 = __builtin_bit_cast(bf16x8, a1w);
}

// ------------------- causal flash attention, D=64 --------------------------
// R12 config (16 q/wave, 4-wave blocks, grid 1024, 32KB LDS) + CROSS-TILE
// PIPELINE: round T computes QK^T(tile T+1) [independent MFMAs] alongside
// softmax+PV(tile T) [scores held in registers from last round] -> MFMA pipe
// busy during softmax. K/V separately double-buffered with staggered
// lookahead: round T issues K(T+2), V(T+1); vmcnt(4) waits last round's 4.
__global__ __launch_bounds__(256) void attn_kernel(
    const __hip_bfloat16* __restrict__ Qb, const __hip_bfloat16* __restrict__ Kb,
    const __hip_bfloat16* __restrict__ Vt, __hip_bfloat16* __restrict__ SA) {
  __shared__ __align__(16) char lds[32768];  // K0|K1|V0|V1 (8KB each)
  const int orig = blockIdx.x;
  const int bh = (orig & 7) * 4 + ((orig >> 3) & 3);  // 4 bh per XCD
  const int qt = 31 - (orig >> 5);                    // heavy first
  const int nt = qt + 1;
  const int b = bh >> 4, h = bh & 15;
  const int tid = threadIdx.x, wave = tid >> 6, lane = tid & 63;
  const int lhi = lane >> 4, llo = lane & 15;
  const int lhi4 = lhi * 4;

  const __hip_bfloat16* qp =
      Qb + ((size_t)bh * 2048 + qt * 64 + wave * 16 + llo) * 64 + lhi * 8;
  bf16x8 q0 = *(const bf16x8*)qp, q1 = *(const bf16x8*)(qp + 32);

  const char* Kg = (const char*)(Kb + (size_t)bh * 2048 * 64);
  const char* Vg = (const char*)(Vt + (size_t)bh * 64 * 2048);

  f32x4 z = {0.f, 0.f, 0.f, 0.f};
  f32x4 o[4];
  float m_s = NEG_INF, l_s = 0.f;
#pragma unroll
  for (int i = 0; i < 4; i++) o[i] = z;
  const int qg = qt * 64 + wave * 16 + llo;    // masking row (lane's q)
  const int qg0 = qt * 64 + wave * 16 + lhi4;  // output row base

  // K tile j lives in lds + (j&1)*8192 ; V tile j in lds + 16384 + (j&1)*8192
#define STAGE_K(c, k0)                                                        \
  {                                                                           \
    char* W = lds + (c)*8192;                                                 \
    _Pragma("unroll") for (int i = 0; i < 2; i++) {                           \
      int ch = i * 256 + tid;                                                 \
      int soff = (ch * 16) ^ (((ch >> 3) & 7) << 4);                          \
      gload16(Kg + (size_t)(k0)*128 + soff, W + (i * 256 + wave * 64) * 16);  \
    }                                                                         \
  }
#define STAGE_V(c, k0)                                                        \
  {                                                                           \
    char* W = lds + 16384 + (c)*8192;                                         \
    _Pragma("unroll") for (int i = 0; i < 2; i++) {                           \
      int ch = i * 256 + tid;                                                 \
      int dd = ch >> 3, c8 = ch & 7;                                          \
      int boff = (c8 * 16) ^ ((dd & 7) << 4);                                 \
      gload16(Vg + (size_t)dd * 4096 + (size_t)(k0)*2 + boff,                 \
              W + (i * 256 + wave * 64) * 16);                                \
    }                                                                         \
  }

  // QK^T swapped for tile tt from kbuf kc -> sdst[j] = C[key][q=llo]
#define QKT(sdst, kc, setz)                                                   \
  {                                                                           \
    const char* KsB = lds + (kc)*8192;                                        \
    _Pragma("unroll") for (int j = 0; j < 4; j++) {                           \
      const int row = j * 16 + llo;                                           \
      const int rx = (row & 7) << 4;                                          \
      bf16x8 bk0 = *(const bf16x8*)(KsB + ((row * 128 + lhi * 16) ^ rx));     \
      bf16x8 bk1 = *(const bf16x8*)(KsB + ((row * 128 + 64 + lhi * 16) ^ rx));\
      if (setz) sdst[j] = z;                                                  \
      sdst[j] = __builtin_amdgcn_mfma_f32_16x16x32_bf16(bk0, q0, sdst[j], 0, 0, 0); \
      sdst[j] = __builtin_amdgcn_mfma_f32_16x16x32_bf16(bk1, q1, sdst[j], 0, 0, 0); \
    }                                                                         \
  }

  // ---- prologue: stage K(0),V(0),K(1); compute QK(0) -> sprev ----
  f32x4 sprev[4];
  STAGE_K(0, 0);
  STAGE_V(0, 0);
  if (nt > 1) {
    STAGE_K(1, 64);
    asm volatile("s_waitcnt vmcnt(4)" ::: "memory");  // K(0) landed
  } else {
    asm volatile("s_waitcnt vmcnt(2)" ::: "memory");  // K(0) landed
  }
  __builtin_amdgcn_s_barrier();
  __builtin_amdgcn_sched_barrier(0);
  QKT(sprev, 0, 1);
  __builtin_amdgcn_sched_barrier(0);
  __builtin_amdgcn_s_barrier();  // all waves done reading kbuf0

  for (int T = 0; T < nt; T++) {
    // issue next stages (into buffers whose previous tiles are fully read)
    if (T + 2 < nt) {
      STAGE_K(T & 1, (T + 2) * 64);
      STAGE_V((T + 1) & 1, (T + 1) * 64);
      asm volatile("s_waitcnt vmcnt(4)" ::: "memory");
    } else if (T + 1 < nt) {
      STAGE_V((T + 1) & 1, (T + 1) * 64);
      asm volatile("s_waitcnt vmcnt(2)" ::: "memory");
    } else {
      asm volatile("s_waitcnt vmcnt(0)" ::: "memory");
    }
    __builtin_amdgcn_s_barrier();
    __builtin_amdgcn_sched_barrier(0);

    const int k0 = T * 64;
    const bool masked = (T == nt - 1);

    // QK^T of tile T+1 (independent of softmax/PV below -> interleaves)
    f32x4 snew[4];
    if (T + 1 < nt) QKT(snew, (T + 1) & 1, 1);

    // softmax + P pack of tile T (scores in sprev)
    bf16x8 ap0, ap1;
    softmax_pack(sprev, masked, k0, qg, lhi4, m_s, l_s, o, ap0, ap1);

    // PV of tile T
    {
      const char* VsB = lds + 16384 + (T & 1) * 8192;
#pragma unroll
      for (int n4 = 0; n4 < 4; n4++) {
        const int d = n4 * 16 + llo;
        const int dx = (d & 7) << 4;
        bf16x8 bv0 = *(const bf16x8*)(VsB + ((d * 128 + lhi * 16) ^ dx));
        bf16x8 bv1 = *(const bf16x8*)(VsB + ((d * 128 + 64 + lhi * 16) ^ dx));
        o[n4] = __builtin_amdgcn_mfma_f32_16x16x32_bf16(ap0, bv0, o[n4], 0, 0, 0);
        o[n4] = __builtin_amdgcn_mfma_f32_16x16x32_bf16(ap1, bv1, o[n4], 0, 0, 0);
      }
    }
    if (T + 1 < nt) {
#pragma unroll
      for (int j = 0; j < 4; j++) sprev[j] = snew[j];
    }
    __builtin_amdgcn_sched_barrier(0);
    __builtin_amdgcn_s_barrier();  // all waves done reading this round's bufs
  }

  // epilogue: reduce l across lhi lanes (permlane), normalize, store
  {
    union { float f; unsigned u; } lu;
    lu.f = l_s;
    u32x2 sp = __builtin_amdgcn_permlane32_swap(lu.u, lu.u, false, false);
    float l1 = __uint_as_float(sp.x) + __uint_as_float(sp.y);
    union { float f; unsigned u; } l2u;
    l2u.f = l1;
    u32x2 tp = __builtin_amdgcn_permlane16_swap(l2u.u, l2u.u, false, false);
    const float l = __uint_as_float(tp.x) + __uint_as_float(tp.y);
    const float inv = 1.f / l;
#pragma unroll
    for (int r = 0; r < 4; r++) {
      const float invr = __shfl(inv, lhi4 + r);
      const size_t ob = ((size_t)b * 2048 + qg0 + r) * 1024 + h * 64;
#pragma unroll
      for (int n4 = 0; n4 < 4; n4++)
        SA[ob + n4 * 16 + llo] = __float2bfloat16(o[n4][r] * invr);
    }
  }
#undef STAGE_K
#undef STAGE_V
#undef QKT
}

// ------------- GEMM3: out = SA @ Wo + bo (fp32 out; 64x128 tiles) ----------
__global__ __launch_bounds__(256) void out_gemm(
    const __hip_bfloat16* __restrict__ SA, const __hip_bfloat16* __restrict__ WoT,
    const float* __restrict__ bo, float* __restrict__ out) {
  __shared__ __align__(16) char As[8192];
  __shared__ __align__(16) char Bs[16384];
  const int m0 = blockIdx.y * 64, n0 = blockIdx.x * 128;
  f32x4 acc[2][4];
  gemm_mainloop_64x128(SA, WoT, 1024, m0, n0, acc, As, Bs);

  const int tid = threadIdx.x, wave = tid >> 6, lane = tid & 63;
  const int lhi = lane >> 4, llo = lane & 15;
  const int wr = wave >> 1, wc = wave & 1;
#pragma unroll
  for (int m2 = 0; m2 < 2; m2++)
#pragma unroll
    for (int n4 = 0; n4 < 4; n4++)
#pragma unroll
      for (int r = 0; r < 4; r++) {
        int mg = m0 + wr * 32 + m2 * 16 + lhi * 4 + r;
        int ng = n0 + wc * 64 + n4 * 16 + llo;
        out[(size_t)mg * 1024 + ng] = acc[m2][n4][r] + bo[ng];
      }
}

extern "C" void kernel_launch(void* const* d_in, const int* in_sizes, int n_in,
                              void* d_out, int out_size, void* d_ws, size_t ws_size,
                              hipStream_t stream) {
  const float* x = (const float*)d_in[0];
  const float* Wkqv = (const float*)d_in[1];
  const float* bkqv = (const float*)d_in[2];
  const float* Wo = (const float*)d_in[3];
  const float* bo = (const float*)d_in[4];
  float* out = (float*)d_out;  // fp32 output (verified R5)

  char* w = (char*)d_ws;
  __hip_bfloat16* WkqvT = (__hip_bfloat16*)(w);            // 3072x1024  (6 MB)
  __hip_bfloat16* WoT = (__hip_bfloat16*)(w + 6291456);    // 1024x1024  (2 MB)
  __hip_bfloat16* Qb = (__hip_bfloat16*)(w + 8388608);     // [B][H][S][64] (8 MB)
  __hip_bfloat16* Kb = (__hip_bfloat16*)(w + 16777216);    // [B][H][S][64] (8 MB)
  __hip_bfloat16* Vt = (__hip_bfloat16*)(w + 25165824);    // [B][H][64][S] (8 MB)
  __hip_bfloat16* SAb = (__hip_bfloat16*)(w + 33554432);   // [B][S][E]     (8 MB)
  __hip_bfloat16* xb = (__hip_bfloat16*)(w + 41943040);    // [B][S][E]     (8 MB)

  prep_kernel<<<8192, 256, 0, stream>>>(x, (u16*)xb, Wkqv, (u16*)WkqvT,
                                        Wo, (u16*)WoT);
  kqv_gemm<<<dim3(24, 32), 256, 0, stream>>>(xb, WkqvT, bkqv, Qb, Kb, Vt);
  attn_kernel<<<1024, 256, 0, stream>>>(Qb, Kb, Vt, SAb);
  out_gemm<<<dim3(8, 64), 256, 0, stream>>>(SAb, WoT, bo, out);
}

// Round 19
// 115.496 us; speedup vs baseline: 1.1825x; 1.0354x over previous
//
#include <hip/hip_runtime.h>
#include <hip/hip_bf16.h>

typedef __attribute__((ext_vector_type(8))) short bf16x8;
typedef __attribute__((ext_vector_type(4))) float f32x4;
typedef __attribute__((ext_vector_type(2))) unsigned u32x2;
typedef __attribute__((ext_vector_type(4))) unsigned u32x4;
typedef unsigned short u16;

#define NEG_INF (-__builtin_inff())

// async global->LDS, 16B per lane. LDS dest must be wave-uniform (HW adds lane*16).
__device__ __forceinline__ void gload16(const void* g, void* l) {
  __builtin_amdgcn_global_load_lds(
      (const __attribute__((address_space(1))) void*)g,
      (__attribute__((address_space(3))) void*)l, 16, 0, 0);
}

__device__ __forceinline__ u16 f2b(float f) {
  union { float f; unsigned u; } v;
  v.f = f;
  unsigned r = v.u + 0x7fff + ((v.u >> 16) & 1);  // RNE
  return (u16)(r >> 16);
}

// pack two f32 -> two bf16 in one u32 (low = a, high = b)
__device__ __forceinline__ unsigned cvt_pk_bf16(float a, float b) {
  unsigned r;
  asm("v_cvt_pk_bf16_f32 %0, %1, %2" : "=v"(r) : "v"(a), "v"(b));
  return r;
}

// ---- fused prep: cvt x -> bf16 | transpose Wkqv | transpose Wo ------------
__global__ __launch_bounds__(256) void prep_kernel(
    const float* __restrict__ x, u16* __restrict__ xb,
    const float* __restrict__ Wkqv, u16* __restrict__ WkqvT,
    const float* __restrict__ Wo, u16* __restrict__ WoT) {
  __shared__ u16 t[32][33];
  const int bid = blockIdx.x;
  const int tid = threadIdx.x;
  if (bid < 4096) {  // cvt: 4 floats/thread
    const int i = bid * 256 + tid;
    float4 v = ((const float4*)x)[i];
    ushort2 a = {f2b(v.x), f2b(v.y)}, b = {f2b(v.z), f2b(v.w)};
    ((ushort2*)xb)[i * 2] = a;
    ((ushort2*)xb)[i * 2 + 1] = b;
    return;
  }
  const int tx = tid & 31, ty = tid >> 5;  // 32x8
  const float* src;
  u16* dst;
  int R, C, bx_, by;
  if (bid < 7168) {  // Wkqv: dst[h][c][r] = bf16(src[h][r][c])
    const int tt = bid - 4096;
    const int bz = tt / 192, rem = tt % 192;
    by = rem / 6; bx_ = rem % 6; R = 1024; C = 192;
    src = Wkqv + (size_t)bz * R * C;
    dst = WkqvT + (size_t)bz * R * C;
  } else {  // Wo
    const int tt = bid - 7168;
    by = tt >> 5; bx_ = tt & 31; R = 1024; C = 1024;
    src = Wo; dst = WoT;
  }
  const int c0 = bx_ * 32, r0 = by * 32;
  for (int i = ty; i < 32; i += 8)
    t[i][tx] = f2b(src[(size_t)(r0 + i) * C + c0 + tx]);
  __syncthreads();
  for (int i = ty; i < 32; i += 8)
    dst[(size_t)(c0 + i) * R + r0 + tx] = t[tx][i];
}

// ------- 128x128x32 bf16 GEMM mainloop, double-buffered + counted vmcnt ----
__device__ __forceinline__ void gemm_mainloop_128(
    const __hip_bfloat16* __restrict__ A, const __hip_bfloat16* __restrict__ Bt,
    int K, int m0, int n0, f32x4 acc[4][4], char* AsB, char* BsB) {
  const int tid = threadIdx.x;
  const int wave = tid >> 6, lane = tid & 63;
  const int lhi = lane >> 4, llo = lane & 15;
  const int wr = wave >> 1, wc = wave & 1;
  f32x4 z = {0.f, 0.f, 0.f, 0.f};
#pragma unroll
  for (int i = 0; i < 4; i++)
#pragma unroll
    for (int j = 0; j < 4; j++) acc[i][j] = z;

#define GSTAGE(c, kk)                                                          \
  {                                                                            \
    char* AsW = AsB + (c)*8192;                                                \
    char* BsW = BsB + (c)*8192;                                                \
    _Pragma("unroll") for (int i = 0; i < 2; i++) {                            \
      int cb = i * 256 + wave * 64;                                            \
      int cq = cb + lane;                                                      \
      gload16(A + ((size_t)(m0 + (cq >> 2)) * K + (kk) + (cq & 3) * 8),        \
              AsW + cb * 16);                                                  \
      gload16(Bt + ((size_t)(n0 + (cq >> 2)) * K + (kk) + (cq & 3) * 8),       \
              BsW + cb * 16);                                                  \
    }                                                                          \
  }

  GSTAGE(0, 0);
  int cur = 0;
  const int nk = K >> 5;
  for (int t = 0; t < nk; t++) {
    if (t + 1 < nk) {
      GSTAGE(cur ^ 1, (t + 1) * 32);
      asm volatile("s_waitcnt vmcnt(4)" ::: "memory");
    } else {
      asm volatile("s_waitcnt vmcnt(0)" ::: "memory");
    }
    __builtin_amdgcn_s_barrier();
    __builtin_amdgcn_sched_barrier(0);

    const char* Ar = AsB + cur * 8192;
    const char* Br = BsB + cur * 8192;
    bf16x8 a[4], b[4];
#pragma unroll
    for (int m4 = 0; m4 < 4; m4++)
      a[m4] = *(const bf16x8*)(Ar + (wr * 64 + m4 * 16 + llo) * 64 + lhi * 16);
#pragma unroll
    for (int n4 = 0; n4 < 4; n4++)
      b[n4] = *(const bf16x8*)(Br + (wc * 64 + n4 * 16 + llo) * 64 + lhi * 16);
#pragma unroll
    for (int m4 = 0; m4 < 4; m4++)
#pragma unroll
      for (int n4 = 0; n4 < 4; n4++)
        acc[m4][n4] =
            __builtin_amdgcn_mfma_f32_16x16x32_bf16(a[m4], b[n4], acc[m4][n4], 0, 0, 0);
    __builtin_amdgcn_sched_barrier(0);
    __builtin_amdgcn_s_barrier();
    cur ^= 1;
  }
#undef GSTAGE
}

// ------- 64x128x32 variant (2 blocks/CU for skinny-M GEMM) -----------------
__device__ __forceinline__ void gemm_mainloop_64x128(
    const __hip_bfloat16* __restrict__ A, const __hip_bfloat16* __restrict__ Bt,
    int K, int m0, int n0, f32x4 acc[2][4], char* AsB, char* BsB) {
  const int tid = threadIdx.x;
  const int wave = tid >> 6, lane = tid & 63;
  const int lhi = lane >> 4, llo = lane & 15;
  const int wr = wave >> 1, wc = wave & 1;
  f32x4 z = {0.f, 0.f, 0.f, 0.f};
#pragma unroll
  for (int i = 0; i < 2; i++)
#pragma unroll
    for (int j = 0; j < 4; j++) acc[i][j] = z;

#define GSTAGE64(c, kk)                                                        \
  {                                                                            \
    char* AsW = AsB + (c)*4096;                                                \
    char* BsW = BsB + (c)*8192;                                                \
    gload16(A + ((size_t)(m0 + (tid >> 2)) * K + (kk) + (tid & 3) * 8),        \
            AsW + (wave * 64) * 16);                                           \
    _Pragma("unroll") for (int i = 0; i < 2; i++) {                            \
      int cb = i * 256 + wave * 64;                                            \
      int cq = cb + lane;                                                      \
      gload16(Bt + ((size_t)(n0 + (cq >> 2)) * K + (kk) + (cq & 3) * 8),       \
              BsW + cb * 16);                                                  \
    }                                                                          \
  }

  GSTAGE64(0, 0);
  int cur = 0;
  const int nk = K >> 5;
  for (int t = 0; t < nk; t++) {
    if (t + 1 < nk) {
      GSTAGE64(cur ^ 1, (t + 1) * 32);
      asm volatile("s_waitcnt vmcnt(3)" ::: "memory");
    } else {
      asm volatile("s_waitcnt vmcnt(0)" ::: "memory");
    }
    __builtin_amdgcn_s_barrier();
    __builtin_amdgcn_sched_barrier(0);

    const char* Ar = AsB + cur * 4096;
    const char* Br = BsB + cur * 8192;
    bf16x8 a[2], b[4];
#pragma unroll
    for (int m2 = 0; m2 < 2; m2++)
      a[m2] = *(const bf16x8*)(Ar + (wr * 32 + m2 * 16 + llo) * 64 + lhi * 16);
#pragma unroll
    for (int n4 = 0; n4 < 4; n4++)
      b[n4] = *(const bf16x8*)(Br + (wc * 64 + n4 * 16 + llo) * 64 + lhi * 16);
#pragma unroll
    for (int m2 = 0; m2 < 2; m2++)
#pragma unroll
      for (int n4 = 0; n4 < 4; n4++)
        acc[m2][n4] =
            __builtin_amdgcn_mfma_f32_16x16x32_bf16(a[m2], b[n4], acc[m2][n4], 0, 0, 0);
    __builtin_amdgcn_sched_barrier(0);
    __builtin_amdgcn_s_barrier();
    cur ^= 1;
  }
#undef GSTAGE64
}

// ------------- GEMM1: kqv = x @ WkqvT^T + bkqv, scatter to K/Q/Vt ----------
// 1-D grid 768 with chunked XCD swizzle: each XCD owns a 12n x 8m region
// whose 96 blocks are exactly co-resident (3/CU x 32 CU) -> working set
// 2MB A + 3MB B fits the XCD's 4MB L2 (vs ~14MB thrash unswizzled).
__global__ __launch_bounds__(256) void kqv_gemm(
    const __hip_bfloat16* __restrict__ x, const __hip_bfloat16* __restrict__ WT,
    const float* __restrict__ bkqv, __hip_bfloat16* __restrict__ Qb,
    __hip_bfloat16* __restrict__ Kb, __hip_bfloat16* __restrict__ Vt) {
  __shared__ __align__(16) char ldsbuf[34816];  // mainloop 32KB | Vsw 128x136 u16
  const int lid = blockIdx.x;
  const int xcd = lid & 7, idx = lid >> 3;      // 96 blocks per XCD
  const int lx = idx % 12, ly = idx / 12;       // 12 n-tiles x 8 m-tiles
  const int n0 = ((xcd & 1) * 12 + lx) * 128;
  const int m0 = ((xcd >> 1) * 8 + ly) * 128;
  f32x4 acc[4][4];
  gemm_mainloop_128(x, WT, 1024, m0, n0, acc, ldsbuf, ldsbuf + 16384);

  const int tid = threadIdx.x, wave = tid >> 6, lane = tid & 63;
  const int lhi = lane >> 4, llo = lane & 15;
  const int wr = wave >> 1, wc = wave & 1;
  u16* Vsw = (u16*)ldsbuf;  // [row 0..127][136] padded (reuse after barrier)
#pragma unroll
  for (int m4 = 0; m4 < 4; m4++)
#pragma unroll
    for (int n4 = 0; n4 < 4; n4++)
#pragma unroll
      for (int r = 0; r < 4; r++) {
        int sp = wr * 64 + m4 * 16 + lhi * 4 + r;   // s - m0
        int row = wc * 64 + n4 * 16 + llo;          // ng - n0
        int mg = m0 + sp;
        int ng = n0 + row;
        int b = mg >> 11, s = mg & 2047;
        int h = ng / 192, f = ng % 192;
        float v = acc[m4][n4][r] + bkqv[h * 192 + f];
        int d = f & 63;
        size_t bh = (size_t)(b * 16 + h);
        if (f < 64)
          Kb[(bh * 2048 + s) * 64 + d] = __float2bfloat16(v);
        else if (f < 128)
          Qb[(bh * 2048 + s) * 64 + d] = __float2bfloat16(v * 0.180336880f);
        else
          Vsw[row * 136 + sp] = f2b(v);
      }
  __syncthreads();
  // coalesced Vt store: each row (V-chunk only) = 256B contiguous in global
#pragma unroll
  for (int it = 0; it < 8; it++) {
    int task = it * 256 + tid;
    int row = task >> 4, c = task & 15;
    int ng = n0 + row, f = ng % 192;
    if (f >= 128) {
      int h = ng / 192, d = f - 128;
      int mg0 = m0 + c * 8;
      int b = mg0 >> 11, s = mg0 & 2047;
      size_t bh = (size_t)(b * 16 + h);
      u32x4 w = *(const u32x4*)&Vsw[row * 136 + c * 8];
      *(u32x4*)((u16*)Vt + (size_t)(bh * 64 + d) * 2048 + s) = w;
    }
  }
}

// ------------------- causal flash attention, D=64 (R12, verified) ----------
// 1 block = one (b,h,q-tile); nt = qt+1 kv-tiles. Grid 1024, 4-5 blocks/CU
// (LDS 32KB). Swapped QK^T; P fully in-register via cvt_pk_bf16 +
// permlane16/32_swap; permlane reduces; defer-max; exp2 domain.
__global__ __launch_bounds__(256) void attn_kernel(
    const __hip_bfloat16* __restrict__ Qb, const __hip_bfloat16* __restrict__ Kb,
    const __hip_bfloat16* __restrict__ Vt, __hip_bfloat16* __restrict__ SA) {
  __shared__ __align__(16) char lds[32768];  // Ks 2x8K | Vs 2x8K
  const int orig = blockIdx.x;
  const int bh = (orig & 7) * 4 + ((orig >> 3) & 3);  // 4 bh per XCD
  const int qt = 31 - (orig >> 5);                    // heavy first
  const int nt = qt + 1;
  const int b = bh >> 4, h = bh & 15;
  const int tid = threadIdx.x, wave = tid >> 6, lane = tid & 63;
  const int lhi = lane >> 4, llo = lane & 15;
  const int lhi4 = lhi * 4;

  const __hip_bfloat16* qp =
      Qb + ((size_t)bh * 2048 + qt * 64 + wave * 16 + llo) * 64 + lhi * 8;
  bf16x8 q0 = *(const bf16x8*)qp, q1 = *(const bf16x8*)(qp + 32);

  const char* Kg = (const char*)(Kb + (size_t)bh * 2048 * 64);
  const char* Vg = (const char*)(Vt + (size_t)bh * 64 * 2048);

  f32x4 z = {0.f, 0.f, 0.f, 0.f};
  f32x4 o[4];
  float m_s = NEG_INF, l_s = 0.f;
#pragma unroll
  for (int i = 0; i < 4; i++) o[i] = z;
  const int qg = qt * 64 + wave * 16 + llo;    // masking row (lane's q)
  const int qg0 = qt * 64 + wave * 16 + lhi4;  // output row base

#define STAGE(c, k0)                                                          \
  {                                                                           \
    char* KsW = lds + (c)*8192;                                               \
    char* VsW = lds + 16384 + (c)*8192;                                       \
    _Pragma("unroll") for (int i = 0; i < 2; i++) {                           \
      int ch = i * 256 + tid;                                                 \
      int soff = (ch * 16) ^ (((ch >> 3) & 7) << 4);                          \
      gload16(Kg + (size_t)(k0)*128 + soff, KsW + (i * 256 + wave * 64) * 16);\
      int dd = ch >> 3, c8 = ch & 7;                                          \
      int boff = (c8 * 16) ^ ((dd & 7) << 4);                                 \
      gload16(Vg + (size_t)dd * 4096 + (size_t)(k0)*2 + boff,                 \
              VsW + (i * 256 + wave * 64) * 16);                              \
    }                                                                         \
  }

  STAGE(0, 0);
  int cur = 0;

  for (int T = 0; T < nt; T++) {
    if (T + 1 < nt) {
      STAGE(cur ^ 1, (T + 1) * 64);
      asm volatile("s_waitcnt vmcnt(4)" ::: "memory");
    } else {
      asm volatile("s_waitcnt vmcnt(0)" ::: "memory");
    }
    __builtin_amdgcn_s_barrier();
    __builtin_amdgcn_sched_barrier(0);

    const int k0 = T * 64;
    const bool masked = (T == nt - 1);
    const char* KsB = lds + cur * 8192;
    const char* VsB = lds + 16384 + cur * 8192;

    // ---- QK^T swapped: s[j] = C[key=j*16+lhi4+r][q=llo] ----
    f32x4 s[4] = {z, z, z, z};
#pragma unroll
    for (int j = 0; j < 4; j++) {
      const int row = j * 16 + llo;
      const int rx = (row & 7) << 4;
      bf16x8 bk0 = *(const bf16x8*)(KsB + ((row * 128 + lhi * 16) ^ rx));
      bf16x8 bk1 = *(const bf16x8*)(KsB + ((row * 128 + 64 + lhi * 16) ^ rx));
      s[j] = __builtin_amdgcn_mfma_f32_16x16x32_bf16(bk0, q0, s[j], 0, 0, 0);
      s[j] = __builtin_amdgcn_mfma_f32_16x16x32_bf16(bk1, q1, s[j], 0, 0, 0);
    }

    // ---- in-lane online softmax (lane owns q=llo; 16 scores local) ----
    if (masked) {
#pragma unroll
      for (int j = 0; j < 4; j++)
#pragma unroll
        for (int r = 0; r < 4; r++)
          if (k0 + j * 16 + lhi4 + r > qg) s[j][r] = NEG_INF;
    }
    float pmax = s[0][0];
#pragma unroll
    for (int j = 0; j < 4; j++)
#pragma unroll
      for (int r = 0; r < 4; r++) pmax = fmaxf(pmax, s[j][r]);
    {  // reduce max across the 4 lhi lanes via permlane swaps (VALU, no DS)
      union { float f; unsigned u; } pu;
      pu.f = pmax;
      u32x2 sp = __builtin_amdgcn_permlane32_swap(pu.u, pu.u, false, false);
      float m1 = fmaxf(__uint_as_float(sp.x), __uint_as_float(sp.y));
      union { float f; unsigned u; } mu;
      mu.f = m1;
      u32x2 tp = __builtin_amdgcn_permlane16_swap(mu.u, mu.u, false, false);
      pmax = fmaxf(__uint_as_float(tp.x), __uint_as_float(tp.y));
    }
    if (!__all(pmax - m_s <= 5.0f)) {  // defer-max: rescale rarely
      const float mn = fmaxf(m_s, pmax);
      const float sc = __builtin_exp2f(m_s - mn);
      m_s = mn;
      l_s *= sc;
#pragma unroll
      for (int r = 0; r < 4; r++) {
        const float scr = __shfl(sc, lhi4 + r);
#pragma unroll
        for (int n4 = 0; n4 < 4; n4++) o[n4][r] *= scr;
      }
    }

    // ---- P in registers: exp2 + pack + permlane redistribution ----
    unsigned pk[4][2];
    float ps = 0.f;
#pragma unroll
    for (int j = 0; j < 4; j++) {
      float p0 = __builtin_exp2f(s[j][0] - m_s);
      float p1 = __builtin_exp2f(s[j][1] - m_s);
      float p2 = __builtin_exp2f(s[j][2] - m_s);
      float p3 = __builtin_exp2f(s[j][3] - m_s);
      ps += (p0 + p1) + (p2 + p3);
      pk[j][0] = cvt_pk_bf16(p0, p1);
      pk[j][1] = cvt_pk_bf16(p2, p3);
    }
    l_s += ps;

    u32x4 a0w, a1w;
#pragma unroll
    for (int u = 0; u < 2; u++) {
      u32x2 sp = __builtin_amdgcn_permlane32_swap(pk[0][u], pk[1][u], false, false);
      u32x2 tp = __builtin_amdgcn_permlane16_swap(sp.x, sp.y, false, false);
      a0w[u] = tp.x;
      a0w[u + 2] = tp.y;
    }
#pragma unroll
    for (int u = 0; u < 2; u++) {
      u32x2 sp = __builtin_amdgcn_permlane32_swap(pk[2][u], pk[3][u], false, false);
      u32x2 tp = __builtin_amdgcn_permlane16_swap(sp.x, sp.y, false, false);
      a1w[u] = tp.x;
      a1w[u + 2] = tp.y;
    }
    bf16x8 ap0 = __builtin_bit_cast(bf16x8, a0w);
    bf16x8 ap1 = __builtin_bit_cast(bf16x8, a1w);

    // ---- PV: o[n4] += P(16x64) . V^T ----
#pragma unroll
    for (int n4 = 0; n4 < 4; n4++) {
      const int d = n4 * 16 + llo;
      const int dx = (d & 7) << 4;
      bf16x8 bv0 = *(const bf16x8*)(VsB + ((d * 128 + lhi * 16) ^ dx));
      bf16x8 bv1 = *(const bf16x8*)(VsB + ((d * 128 + 64 + lhi * 16) ^ dx));
      o[n4] = __builtin_amdgcn_mfma_f32_16x16x32_bf16(ap0, bv0, o[n4], 0, 0, 0);
      o[n4] = __builtin_amdgcn_mfma_f32_16x16x32_bf16(ap1, bv1, o[n4], 0, 0, 0);
    }
    __builtin_amdgcn_sched_barrier(0);
    __builtin_amdgcn_s_barrier();  // all waves done reading buf[cur]
    cur ^= 1;
  }

  // epilogue: reduce l across lhi lanes (permlane), normalize, store
  {
    union { float f; unsigned u; } lu;
    lu.f = l_s;
    u32x2 sp = __builtin_amdgcn_permlane32_swap(lu.u, lu.u, false, false);
    float l1 = __uint_as_float(sp.x) + __uint_as_float(sp.y);
    union { float f; unsigned u; } l2u;
    l2u.f = l1;
    u32x2 tp = __builtin_amdgcn_permlane16_swap(l2u.u, l2u.u, false, false);
    const float l = __uint_as_float(tp.x) + __uint_as_float(tp.y);
    const float inv = 1.f / l;
#pragma unroll
    for (int r = 0; r < 4; r++) {
      const float invr = __shfl(inv, lhi4 + r);
      const size_t ob = ((size_t)b * 2048 + qg0 + r) * 1024 + h * 64;
#pragma unroll
      for (int n4 = 0; n4 < 4; n4++)
        SA[ob + n4 * 16 + llo] = __float2bfloat16(o[n4][r] * invr);
    }
  }
#undef STAGE
}

// ------------- GEMM3: out = SA @ Wo + bo (fp32 out; 64x128 tiles) ----------
// 1-D grid 512 with chunked XCD swizzle: each XCD = 8n x 8m region, 64
// co-resident blocks (2/CU), working set 1MB A + 2MB B fits L2.
__global__ __launch_bounds__(256) void out_gemm(
    const __hip_bfloat16* __restrict__ SA, const __hip_bfloat16* __restrict__ WoT,
    const float* __restrict__ bo, float* __restrict__ out) {
  __shared__ __align__(16) char As[8192];
  __shared__ __align__(16) char Bs[16384];
  const int lid = blockIdx.x;
  const int xcd = lid & 7, idx = lid >> 3;  // 64 blocks per XCD
  const int n0 = (idx & 7) * 128;
  const int m0 = (xcd * 8 + (idx >> 3)) * 64;
  f32x4 acc[2][4];
  gemm_mainloop_64x128(SA, WoT, 1024, m0, n0, acc, As, Bs);

  const int tid = threadIdx.x, wave = tid >> 6, lane = tid & 63;
  const int lhi = lane >> 4, llo = lane & 15;
  const int wr = wave >> 1, wc = wave & 1;
#pragma unroll
  for (int m2 = 0; m2 < 2; m2++)
#pragma unroll
    for (int n4 = 0; n4 < 4; n4++)
#pragma unroll
      for (int r = 0; r < 4; r++) {
        int mg = m0 + wr * 32 + m2 * 16 + lhi * 4 + r;
        int ng = n0 + wc * 64 + n4 * 16 + llo;
        out[(size_t)mg * 1024 + ng] = acc[m2][n4][r] + bo[ng];
      }
}

extern "C" void kernel_launch(void* const* d_in, const int* in_sizes, int n_in,
                              void* d_out, int out_size, void* d_ws, size_t ws_size,
                              hipStream_t stream) {
  const float* x = (const float*)d_in[0];
  const float* Wkqv = (const float*)d_in[1];
  const float* bkqv = (const float*)d_in[2];
  const float* Wo = (const float*)d_in[3];
  const float* bo = (const float*)d_in[4];
  float* out = (float*)d_out;  // fp32 output (verified R5)

  char* w = (char*)d_ws;
  __hip_bfloat16* WkqvT = (__hip_bfloat16*)(w);            // 3072x1024  (6 MB)
  __hip_bfloat16* WoT = (__hip_bfloat16*)(w + 6291456);    // 1024x1024  (2 MB)
  __hip_bfloat16* Qb = (__hip_bfloat16*)(w + 8388608);     // [B][H][S][64] (8 MB)
  __hip_bfloat16* Kb = (__hip_bfloat16*)(w + 16777216);    // [B][H][S][64] (8 MB)
  __hip_bfloat16* Vt = (__hip_bfloat16*)(w + 25165824);    // [B][H][64][S] (8 MB)
  __hip_bfloat16* SAb = (__hip_bfloat16*)(w + 33554432);   // [B][S][E]     (8 MB)
  __hip_bfloat16* xb = (__hip_bfloat16*)(w + 41943040);    // [B][S][E]     (8 MB)

  prep_kernel<<<8192, 256, 0, stream>>>(x, (u16*)xb, Wkqv, (u16*)WkqvT,
                                        Wo, (u16*)WoT);
  kqv_gemm<<<768, 256, 0, stream>>>(xb, WkqvT, bkqv, Qb, Kb, Vt);
  attn_kernel<<<1024, 256, 0, stream>>>(Qb, Kb, Vt, SAb);
  out_gemm<<<512, 256, 0, stream>>>(SAb, WoT, bo, out);
}

// Round 20
// 114.941 us; speedup vs baseline: 1.1882x; 1.0048x over previous
//
#include <hip/hip_runtime.h>
#include <hip/hip_bf16.h>

typedef __attribute__((ext_vector_type(8))) short bf16x8;
typedef __attribute__((ext_vector_type(4))) float f32x4;
typedef __attribute__((ext_vector_type(2))) unsigned u32x2;
typedef __attribute__((ext_vector_type(4))) unsigned u32x4;
typedef unsigned short u16;

#define NEG_INF (-__builtin_inff())

// async global->LDS, 16B per lane. LDS dest must be wave-uniform (HW adds lane*16).
__device__ __forceinline__ void gload16(const void* g, void* l) {
  __builtin_amdgcn_global_load_lds(
      (const __attribute__((address_space(1))) void*)g,
      (__attribute__((address_space(3))) void*)l, 16, 0, 0);
}

__device__ __forceinline__ u16 f2b(float f) {
  union { float f; unsigned u; } v;
  v.f = f;
  unsigned r = v.u + 0x7fff + ((v.u >> 16) & 1);  // RNE
  return (u16)(r >> 16);
}

// pack two f32 -> two bf16 in one u32 (low = a, high = b)
__device__ __forceinline__ unsigned cvt_pk_bf16(float a, float b) {
  unsigned r;
  asm("v_cvt_pk_bf16_f32 %0, %1, %2" : "=v"(r) : "v"(a), "v"(b));
  return r;
}

// ---- fused prep: cvt x -> bf16 (8/thread) | transpose Wkqv | transpose Wo -
__global__ __launch_bounds__(256) void prep_kernel(
    const float* __restrict__ x, u16* __restrict__ xb,
    const float* __restrict__ Wkqv, u16* __restrict__ WkqvT,
    const float* __restrict__ Wo, u16* __restrict__ WoT) {
  __shared__ u16 t[32][33];
  const int bid = blockIdx.x;
  const int tid = threadIdx.x;
  if (bid < 2048) {  // cvt: 8 floats/thread (two float4s)
    const int i = (bid * 256 + tid) * 2;
#pragma unroll
    for (int u = 0; u < 2; u++) {
      float4 v = ((const float4*)x)[i + u];
      ushort2 a = {f2b(v.x), f2b(v.y)}, b = {f2b(v.z), f2b(v.w)};
      ((ushort2*)xb)[(i + u) * 2] = a;
      ((ushort2*)xb)[(i + u) * 2 + 1] = b;
    }
    return;
  }
  const int tx = tid & 31, ty = tid >> 5;  // 32x8
  const float* src;
  u16* dst;
  int R, C, bx_, by;
  if (bid < 5120) {  // Wkqv: dst[h][c][r] = bf16(src[h][r][c])
    const int tt = bid - 2048;
    const int bz = tt / 192, rem = tt % 192;
    by = rem / 6; bx_ = rem % 6; R = 1024; C = 192;
    src = Wkqv + (size_t)bz * R * C;
    dst = WkqvT + (size_t)bz * R * C;
  } else {  // Wo
    const int tt = bid - 5120;
    by = tt >> 5; bx_ = tt & 31; R = 1024; C = 1024;
    src = Wo; dst = WoT;
  }
  const int c0 = bx_ * 32, r0 = by * 32;
  for (int i = ty; i < 32; i += 8)
    t[i][tx] = f2b(src[(size_t)(r0 + i) * C + c0 + tx]);
  __syncthreads();
  for (int i = ty; i < 32; i += 8)
    dst[(size_t)(c0 + i) * R + r0 + tx] = t[tx][i];
}

// ------- 128x128x32 bf16 GEMM mainloop, double-buffered + counted vmcnt ----
__device__ __forceinline__ void gemm_mainloop_128(
    const __hip_bfloat16* __restrict__ A, const __hip_bfloat16* __restrict__ Bt,
    int K, int m0, int n0, f32x4 acc[4][4], char* AsB, char* BsB) {
  const int tid = threadIdx.x;
  const int wave = tid >> 6, lane = tid & 63;
  const int lhi = lane >> 4, llo = lane & 15;
  const int wr = wave >> 1, wc = wave & 1;
  f32x4 z = {0.f, 0.f, 0.f, 0.f};
#pragma unroll
  for (int i = 0; i < 4; i++)
#pragma unroll
    for (int j = 0; j < 4; j++) acc[i][j] = z;

#define GSTAGE(c, kk)                                                          \
  {                                                                            \
    char* AsW = AsB + (c)*8192;                                                \
    char* BsW = BsB + (c)*8192;                                                \
    _Pragma("unroll") for (int i = 0; i < 2; i++) {                            \
      int cb = i * 256 + wave * 64;                                            \
      int cq = cb + lane;                                                      \
      gload16(A + ((size_t)(m0 + (cq >> 2)) * K + (kk) + (cq & 3) * 8),        \
              AsW + cb * 16);                                                  \
      gload16(Bt + ((size_t)(n0 + (cq >> 2)) * K + (kk) + (cq & 3) * 8),       \
              BsW + cb * 16);                                                  \
    }                                                                          \
  }

  GSTAGE(0, 0);
  int cur = 0;
  const int nk = K >> 5;
  for (int t = 0; t < nk; t++) {
    if (t + 1 < nk) {
      GSTAGE(cur ^ 1, (t + 1) * 32);
      asm volatile("s_waitcnt vmcnt(4)" ::: "memory");
    } else {
      asm volatile("s_waitcnt vmcnt(0)" ::: "memory");
    }
    __builtin_amdgcn_s_barrier();
    __builtin_amdgcn_sched_barrier(0);

    const char* Ar = AsB + cur * 8192;
    const char* Br = BsB + cur * 8192;
    bf16x8 a[4], b[4];
#pragma unroll
    for (int m4 = 0; m4 < 4; m4++)
      a[m4] = *(const bf16x8*)(Ar + (wr * 64 + m4 * 16 + llo) * 64 + lhi * 16);
#pragma unroll
    for (int n4 = 0; n4 < 4; n4++)
      b[n4] = *(const bf16x8*)(Br + (wc * 64 + n4 * 16 + llo) * 64 + lhi * 16);
#pragma unroll
    for (int m4 = 0; m4 < 4; m4++)
#pragma unroll
      for (int n4 = 0; n4 < 4; n4++)
        acc[m4][n4] =
            __builtin_amdgcn_mfma_f32_16x16x32_bf16(a[m4], b[n4], acc[m4][n4], 0, 0, 0);
    __builtin_amdgcn_sched_barrier(0);
    __builtin_amdgcn_s_barrier();
    cur ^= 1;
  }
#undef GSTAGE
}

// ------- 64x128x32 variant (2 blocks/CU for skinny-M GEMM) -----------------
__device__ __forceinline__ void gemm_mainloop_64x128(
    const __hip_bfloat16* __restrict__ A, const __hip_bfloat16* __restrict__ Bt,
    int K, int m0, int n0, f32x4 acc[2][4], char* AsB, char* BsB) {
  const int tid = threadIdx.x;
  const int wave = tid >> 6, lane = tid & 63;
  const int lhi = lane >> 4, llo = lane & 15;
  const int wr = wave >> 1, wc = wave & 1;
  f32x4 z = {0.f, 0.f, 0.f, 0.f};
#pragma unroll
  for (int i = 0; i < 2; i++)
#pragma unroll
    for (int j = 0; j < 4; j++) acc[i][j] = z;

#define GSTAGE64(c, kk)                                                        \
  {                                                                            \
    char* AsW = AsB + (c)*4096;                                                \
    char* BsW = BsB + (c)*8192;                                                \
    gload16(A + ((size_t)(m0 + (tid >> 2)) * K + (kk) + (tid & 3) * 8),        \
            AsW + (wave * 64) * 16);                                           \
    _Pragma("unroll") for (int i = 0; i < 2; i++) {                            \
      int cb = i * 256 + wave * 64;                                            \
      int cq = cb + lane;                                                      \
      gload16(Bt + ((size_t)(n0 + (cq >> 2)) * K + (kk) + (cq & 3) * 8),       \
              BsW + cb * 16);                                                  \
    }                                                                          \
  }

  GSTAGE64(0, 0);
  int cur = 0;
  const int nk = K >> 5;
  for (int t = 0; t < nk; t++) {
    if (t + 1 < nk) {
      GSTAGE64(cur ^ 1, (t + 1) * 32);
      asm volatile("s_waitcnt vmcnt(3)" ::: "memory");
    } else {
      asm volatile("s_waitcnt vmcnt(0)" ::: "memory");
    }
    __builtin_amdgcn_s_barrier();
    __builtin_amdgcn_sched_barrier(0);

    const char* Ar = AsB + cur * 4096;
    const char* Br = BsB + cur * 8192;
    bf16x8 a[2], b[4];
#pragma unroll
    for (int m2 = 0; m2 < 2; m2++)
      a[m2] = *(const bf16x8*)(Ar + (wr * 32 + m2 * 16 + llo) * 64 + lhi * 16);
#pragma unroll
    for (int n4 = 0; n4 < 4; n4++)
      b[n4] = *(const bf16x8*)(Br + (wc * 64 + n4 * 16 + llo) * 64 + lhi * 16);
#pragma unroll
    for (int m2 = 0; m2 < 2; m2++)
#pragma unroll
      for (int n4 = 0; n4 < 4; n4++)
        acc[m2][n4] =
            __builtin_amdgcn_mfma_f32_16x16x32_bf16(a[m2], b[n4], acc[m2][n4], 0, 0, 0);
    __builtin_amdgcn_sched_barrier(0);
    __builtin_amdgcn_s_barrier();
    cur ^= 1;
  }
#undef GSTAGE64
}

// ------------- GEMM1: kqv = x @ WkqvT^T + bkqv, scatter to K/Q/Vt ----------
// 1-D grid 768, chunked XCD swizzle (12n x 8m region per XCD).
__global__ __launch_bounds__(256) void kqv_gemm(
    const __hip_bfloat16* __restrict__ x, const __hip_bfloat16* __restrict__ WT,
    const float* __restrict__ bkqv, __hip_bfloat16* __restrict__ Qb,
    __hip_bfloat16* __restrict__ Kb, __hip_bfloat16* __restrict__ Vt) {
  __shared__ __align__(16) char ldsbuf[34816];  // mainloop 32KB | Vsw 128x136 u16
  const int lid = blockIdx.x;
  const int xcd = lid & 7, idx = lid >> 3;      // 96 blocks per XCD
  const int lx = idx % 12, ly = idx / 12;       // 12 n-tiles x 8 m-tiles
  const int n0 = ((xcd & 1) * 12 + lx) * 128;
  const int m0 = ((xcd >> 1) * 8 + ly) * 128;
  f32x4 acc[4][4];
  gemm_mainloop_128(x, WT, 1024, m0, n0, acc, ldsbuf, ldsbuf + 16384);

  const int tid = threadIdx.x, wave = tid >> 6, lane = tid & 63;
  const int lhi = lane >> 4, llo = lane & 15;
  const int wr = wave >> 1, wc = wave & 1;
  u16* Vsw = (u16*)ldsbuf;  // [row 0..127][136] padded (reuse after barrier)
#pragma unroll
  for (int m4 = 0; m4 < 4; m4++)
#pragma unroll
    for (int n4 = 0; n4 < 4; n4++)
#pragma unroll
      for (int r = 0; r < 4; r++) {
        int sp = wr * 64 + m4 * 16 + lhi * 4 + r;   // s - m0
        int row = wc * 64 + n4 * 16 + llo;          // ng - n0
        int mg = m0 + sp;
        int ng = n0 + row;
        int b = mg >> 11, s = mg & 2047;
        int h = ng / 192, f = ng % 192;
        float v = acc[m4][n4][r] + bkqv[h * 192 + f];
        int d = f & 63;
        size_t bh = (size_t)(b * 16 + h);
        if (f < 64)
          Kb[(bh * 2048 + s) * 64 + d] = __float2bfloat16(v);
        else if (f < 128)
          Qb[(bh * 2048 + s) * 64 + d] = __float2bfloat16(v * 0.180336880f);
        else
          Vsw[row * 136 + sp] = f2b(v);
      }
  __syncthreads();
  // coalesced Vt store: each row (V-chunk only) = 256B contiguous in global
#pragma unroll
  for (int it = 0; it < 8; it++) {
    int task = it * 256 + tid;
    int row = task >> 4, c = task & 15;
    int ng = n0 + row, f = ng % 192;
    if (f >= 128) {
      int h = ng / 192, d = f - 128;
      int mg0 = m0 + c * 8;
      int b = mg0 >> 11, s = mg0 & 2047;
      size_t bh = (size_t)(b * 16 + h);
      u32x4 w = *(const u32x4*)&Vsw[row * 136 + c * 8];
      *(u32x4*)((u16*)Vt + (size_t)(bh * 64 + d) * 2048 + s) = w;
    }
  }
}

// ------------------- causal flash attention, D=64 (R12 + T5 setprio) -------
__global__ __launch_bounds__(256) void attn_kernel(
    const __hip_bfloat16* __restrict__ Qb, const __hip_bfloat16* __restrict__ Kb,
    const __hip_bfloat16* __restrict__ Vt, __hip_bfloat16* __restrict__ SA) {
  __shared__ __align__(16) char lds[32768];  // Ks 2x8K | Vs 2x8K
  const int orig = blockIdx.x;
  const int bh = (orig & 7) * 4 + ((orig >> 3) & 3);  // 4 bh per XCD
  const int qt = 31 - (orig >> 5);                    // heavy first
  const int nt = qt + 1;
  const int b = bh >> 4, h = bh & 15;
  const int tid = threadIdx.x, wave = tid >> 6, lane = tid & 63;
  const int lhi = lane >> 4, llo = lane & 15;
  const int lhi4 = lhi * 4;

  const __hip_bfloat16* qp =
      Qb + ((size_t)bh * 2048 + qt * 64 + wave * 16 + llo) * 64 + lhi * 8;
  bf16x8 q0 = *(const bf16x8*)qp, q1 = *(const bf16x8*)(qp + 32);

  const char* Kg = (const char*)(Kb + (size_t)bh * 2048 * 64);
  const char* Vg = (const char*)(Vt + (size_t)bh * 64 * 2048);

  f32x4 z = {0.f, 0.f, 0.f, 0.f};
  f32x4 o[4];
  float m_s = NEG_INF, l_s = 0.f;
#pragma unroll
  for (int i = 0; i < 4; i++) o[i] = z;
  const int qg = qt * 64 + wave * 16 + llo;    // masking row (lane's q)
  const int qg0 = qt * 64 + wave * 16 + lhi4;  // output row base

#define STAGE(c, k0)                                                          \
  {                                                                           \
    char* KsW = lds + (c)*8192;                                               \
    char* VsW = lds + 16384 + (c)*8192;                                       \
    _Pragma("unroll") for (int i = 0; i < 2; i++) {                           \
      int ch = i * 256 + tid;                                                 \
      int soff = (ch * 16) ^ (((ch >> 3) & 7) << 4);                          \
      gload16(Kg + (size_t)(k0)*128 + soff, KsW + (i * 256 + wave * 64) * 16);\
      int dd = ch >> 3, c8 = ch & 7;                                          \
      int boff = (c8 * 16) ^ ((dd & 7) << 4);                                 \
      gload16(Vg + (size_t)dd * 4096 + (size_t)(k0)*2 + boff,                 \
              VsW + (i * 256 + wave * 64) * 16);                              \
    }                                                                         \
  }

  STAGE(0, 0);
  int cur = 0;

  for (int T = 0; T < nt; T++) {
    if (T + 1 < nt) {
      STAGE(cur ^ 1, (T + 1) * 64);
      asm volatile("s_waitcnt vmcnt(4)" ::: "memory");
    } else {
      asm volatile("s_waitcnt vmcnt(0)" ::: "memory");
    }
    __builtin_amdgcn_s_barrier();
    __builtin_amdgcn_sched_barrier(0);

    const int k0 = T * 64;
    const bool masked = (T == nt - 1);
    const char* KsB = lds + cur * 8192;
    const char* VsB = lds + 16384 + cur * 8192;

    // ---- QK^T swapped: s[j] = C[key=j*16+lhi4+r][q=llo] ----
    f32x4 s[4] = {z, z, z, z};
#pragma unroll
    for (int j = 0; j < 4; j++) {
      const int row = j * 16 + llo;
      const int rx = (row & 7) << 4;
      bf16x8 bk0 = *(const bf16x8*)(KsB + ((row * 128 + lhi * 16) ^ rx));
      bf16x8 bk1 = *(const bf16x8*)(KsB + ((row * 128 + 64 + lhi * 16) ^ rx));
      __builtin_amdgcn_s_setprio(1);
      s[j] = __builtin_amdgcn_mfma_f32_16x16x32_bf16(bk0, q0, s[j], 0, 0, 0);
      s[j] = __builtin_amdgcn_mfma_f32_16x16x32_bf16(bk1, q1, s[j], 0, 0, 0);
      __builtin_amdgcn_s_setprio(0);
    }

    // ---- in-lane online softmax (lane owns q=llo; 16 scores local) ----
    if (masked) {
#pragma unroll
      for (int j = 0; j < 4; j++)
#pragma unroll
        for (int r = 0; r < 4; r++)
          if (k0 + j * 16 + lhi4 + r > qg) s[j][r] = NEG_INF;
    }
    float pmax = s[0][0];
#pragma unroll
    for (int j = 0; j < 4; j++)
#pragma unroll
      for (int r = 0; r < 4; r++) pmax = fmaxf(pmax, s[j][r]);
    {  // reduce max across the 4 lhi lanes via permlane swaps (VALU, no DS)
      union { float f; unsigned u; } pu;
      pu.f = pmax;
      u32x2 sp = __builtin_amdgcn_permlane32_swap(pu.u, pu.u, false, false);
      float m1 = fmaxf(__uint_as_float(sp.x), __uint_as_float(sp.y));
      union { float f; unsigned u; } mu;
      mu.f = m1;
      u32x2 tp = __builtin_amdgcn_permlane16_swap(mu.u, mu.u, false, false);
      pmax = fmaxf(__uint_as_float(tp.x), __uint_as_float(tp.y));
    }
    if (!__all(pmax - m_s <= 5.0f)) {  // defer-max: rescale rarely
      const float mn = fmaxf(m_s, pmax);
      const float sc = __builtin_exp2f(m_s - mn);
      m_s = mn;
      l_s *= sc;
#pragma unroll
      for (int r = 0; r < 4; r++) {
        const float scr = __shfl(sc, lhi4 + r);
#pragma unroll
        for (int n4 = 0; n4 < 4; n4++) o[n4][r] *= scr;
      }
    }

    // ---- P in registers: exp2 + pack + permlane redistribution ----
    unsigned pk[4][2];
    float ps = 0.f;
#pragma unroll
    for (int j = 0; j < 4; j++) {
      float p0 = __builtin_exp2f(s[j][0] - m_s);
      float p1 = __builtin_exp2f(s[j][1] - m_s);
      float p2 = __builtin_exp2f(s[j][2] - m_s);
      float p3 = __builtin_exp2f(s[j][3] - m_s);
      ps += (p0 + p1) + (p2 + p3);
      pk[j][0] = cvt_pk_bf16(p0, p1);
      pk[j][1] = cvt_pk_bf16(p2, p3);
    }
    l_s += ps;

    u32x4 a0w, a1w;
#pragma unroll
    for (int u = 0; u < 2; u++) {
      u32x2 sp = __builtin_amdgcn_permlane32_swap(pk[0][u], pk[1][u], false, false);
      u32x2 tp = __builtin_amdgcn_permlane16_swap(sp.x, sp.y, false, false);
      a0w[u] = tp.x;
      a0w[u + 2] = tp.y;
    }
#pragma unroll
    for (int u = 0; u < 2; u++) {
      u32x2 sp = __builtin_amdgcn_permlane32_swap(pk[2][u], pk[3][u], false, false);
      u32x2 tp = __builtin_amdgcn_permlane16_swap(sp.x, sp.y, false, false);
      a1w[u] = tp.x;
      a1w[u + 2] = tp.y;
    }
    bf16x8 ap0 = __builtin_bit_cast(bf16x8, a0w);
    bf16x8 ap1 = __builtin_bit_cast(bf16x8, a1w);

    // ---- PV: o[n4] += P(16x64) . V^T ----
#pragma unroll
    for (int n4 = 0; n4 < 4; n4++) {
      const int d = n4 * 16 + llo;
      const int dx = (d & 7) << 4;
      bf16x8 bv0 = *(const bf16x8*)(VsB + ((d * 128 + lhi * 16) ^ dx));
      bf16x8 bv1 = *(const bf16x8*)(VsB + ((d * 128 + 64 + lhi * 16) ^ dx));
      __builtin_amdgcn_s_setprio(1);
      o[n4] = __builtin_amdgcn_mfma_f32_16x16x32_bf16(ap0, bv0, o[n4], 0, 0, 0);
      o[n4] = __builtin_amdgcn_mfma_f32_16x16x32_bf16(ap1, bv1, o[n4], 0, 0, 0);
      __builtin_amdgcn_s_setprio(0);
    }
    __builtin_amdgcn_sched_barrier(0);
    __builtin_amdgcn_s_barrier();  // all waves done reading buf[cur]
    cur ^= 1;
  }

  // epilogue: reduce l across lhi lanes (permlane), normalize, store
  {
    union { float f; unsigned u; } lu;
    lu.f = l_s;
    u32x2 sp = __builtin_amdgcn_permlane32_swap(lu.u, lu.u, false, false);
    float l1 = __uint_as_float(sp.x) + __uint_as_float(sp.y);
    union { float f; unsigned u; } l2u;
    l2u.f = l1;
    u32x2 tp = __builtin_amdgcn_permlane16_swap(l2u.u, l2u.u, false, false);
    const float l = __uint_as_float(tp.x) + __uint_as_float(tp.y);
    const float inv = 1.f / l;
#pragma unroll
    for (int r = 0; r < 4; r++) {
      const float invr = __shfl(inv, lhi4 + r);
      const size_t ob = ((size_t)b * 2048 + qg0 + r) * 1024 + h * 64;
#pragma unroll
      for (int n4 = 0; n4 < 4; n4++)
        SA[ob + n4 * 16 + llo] = __float2bfloat16(o[n4][r] * invr);
    }
  }
#undef STAGE
}

// ------------- GEMM3: out = SA @ Wo + bo (fp32 out; 64x128 tiles) ----------
__global__ __launch_bounds__(256) void out_gemm(
    const __hip_bfloat16* __restrict__ SA, const __hip_bfloat16* __restrict__ WoT,
    const float* __restrict__ bo, float* __restrict__ out) {
  __shared__ __align__(16) char As[8192];
  __shared__ __align__(16) char Bs[16384];
  const int lid = blockIdx.x;
  const int xcd = lid & 7, idx = lid >> 3;  // 64 blocks per XCD
  const int n0 = (idx & 7) * 128;
  const int m0 = (xcd * 8 + (idx >> 3)) * 64;
  f32x4 acc[2][4];
  gemm_mainloop_64x128(SA, WoT, 1024, m0, n0, acc, As, Bs);

  const int tid = threadIdx.x, wave = tid >> 6, lane = tid & 63;
  const int lhi = lane >> 4, llo = lane & 15;
  const int wr = wave >> 1, wc = wave & 1;
#pragma unroll
  for (int m2 = 0; m2 < 2; m2++)
#pragma unroll
    for (int n4 = 0; n4 < 4; n4++)
#pragma unroll
      for (int r = 0; r < 4; r++) {
        int mg = m0 + wr * 32 + m2 * 16 + lhi * 4 + r;
        int ng = n0 + wc * 64 + n4 * 16 + llo;
        out[(size_t)mg * 1024 + ng] = acc[m2][n4][r] + bo[ng];
      }
}

extern "C" void kernel_launch(void* const* d_in, const int* in_sizes, int n_in,
                              void* d_out, int out_size, void* d_ws, size_t ws_size,
                              hipStream_t stream) {
  const float* x = (const float*)d_in[0];
  const float* Wkqv = (const float*)d_in[1];
  const float* bkqv = (const float*)d_in[2];
  const float* Wo = (const float*)d_in[3];
  const float* bo = (const float*)d_in[4];
  float* out = (float*)d_out;  // fp32 output (verified R5)

  char* w = (char*)d_ws;
  __hip_bfloat16* WkqvT = (__hip_bfloat16*)(w);            // 3072x1024  (6 MB)
  __hip_bfloat16* WoT = (__hip_bfloat16*)(w + 6291456);    // 1024x1024  (2 MB)
  __hip_bfloat16* Qb = (__hip_bfloat16*)(w + 8388608);     // [B][H][S][64] (8 MB)
  __hip_bfloat16* Kb = (__hip_bfloat16*)(w + 16777216);    // [B][H][S][64] (8 MB)
  __hip_bfloat16* Vt = (__hip_bfloat16*)(w + 25165824);    // [B][H][64][S] (8 MB)
  __hip_bfloat16* SAb = (__hip_bfloat16*)(w + 33554432);   // [B][S][E]     (8 MB)
  __hip_bfloat16* xb = (__hip_bfloat16*)(w + 41943040);    // [B][S][E]     (8 MB)

  prep_kernel<<<6144, 256, 0, stream>>>(x, (u16*)xb, Wkqv, (u16*)WkqvT,
                                        Wo, (u16*)WoT);
  kqv_gemm<<<768, 256, 0, stream>>>(xb, WkqvT, bkqv, Qb, Kb, Vt);
  attn_kernel<<<1024, 256, 0, stream>>>(Qb, Kb, Vt, SAb);
  out_gemm<<<512, 256, 0, stream>>>(SAb, WoT, bo, out);
}